// Round 1
// baseline (759.070 us; speedup 1.0000x reference)
//
#include <hip/hip_runtime.h>
#include <cstddef>

// Problem constants (match reference)
constexpr int NN = 20000;   // nodes
constexpr int NE = 320000;  // edges
constexpr int NHEAD = 4;
constexpr int ND = 128;     // per-head dim
constexpr int HD = 512;     // H*D
constexpr float NEG_SLOPE = 0.2f;

// ---------------- CSR build ----------------
__global__ __launch_bounds__(256) void hist_kernel(const int* __restrict__ dst,
                                                   int* __restrict__ cnt) {
  int t = blockIdx.x * 256 + threadIdx.x;
  if (t < NE) atomicAdd(&cnt[dst[t]], 1);
}

// single-block exclusive scan of NN counts -> offs[0..NN]
__global__ __launch_bounds__(1024) void scan_kernel(const int* __restrict__ cnt,
                                                    int* __restrict__ offs) {
  __shared__ int tmp[1024];
  __shared__ int carry_s;
  int t = threadIdx.x;
  if (t == 0) carry_s = 0;
  __syncthreads();
  for (int base = 0; base < NN; base += 1024) {
    int v = (base + t < NN) ? cnt[base + t] : 0;
    tmp[t] = v;
    __syncthreads();
    for (int off = 1; off < 1024; off <<= 1) {
      int x = (t >= off) ? tmp[t - off] : 0;
      __syncthreads();
      tmp[t] += x;
      __syncthreads();
    }
    int incl = tmp[t];
    int carry = carry_s;
    __syncthreads();
    if (base + t < NN) offs[base + t] = carry + incl - v;
    if (t == 1023) carry_s = carry + incl;
    __syncthreads();
  }
  if (t == 0) offs[NN] = carry_s;
}

__global__ __launch_bounds__(256) void copy_kernel(const int* __restrict__ offs,
                                                   int* __restrict__ cursor) {
  int t = blockIdx.x * 256 + threadIdx.x;
  if (t < NN) cursor[t] = offs[t];
}

__global__ __launch_bounds__(256) void fill_kernel(const int* __restrict__ dst,
                                                   int* __restrict__ cursor,
                                                   int* __restrict__ eids) {
  int t = blockIdx.x * 256 + threadIdx.x;
  if (t < NE) {
    int d = dst[t];
    int p = atomicAdd(&cursor[d], 1);
    eids[p] = t;
  }
}

// ---------------- fp32 tiled GEMM: C[N,M] = A[N,K] @ B[K,M] ----------------
// BM=BN=64, BK=16, 256 threads, 4x4 per thread.
__global__ __launch_bounds__(256) void sgemm_kernel(const float* __restrict__ A,
                                                    const float* __restrict__ B,
                                                    float* __restrict__ C,
                                                    int N, int K, int M) {
  __shared__ float As[16][65];
  __shared__ float Bs[16][68];
  int t = threadIdx.x;
  int tx = t & 15, ty = t >> 4;
  int rowBase = blockIdx.x * 64;
  int colBase = blockIdx.y * 64;
  float c[4][4] = {};
  int aRow = t >> 2;           // 0..63
  int aCol = (t & 3) * 4;      // 0,4,8,12
  int bRow = t >> 4;           // 0..15
  int bCol = (t & 15) * 4;     // 0..60

  for (int k0 = 0; k0 < K; k0 += 16) {
    float4 av = make_float4(0.f, 0.f, 0.f, 0.f);
    int ar = rowBase + aRow;
    if (ar < N) av = *reinterpret_cast<const float4*>(&A[(size_t)ar * K + k0 + aCol]);
    As[aCol + 0][aRow] = av.x;
    As[aCol + 1][aRow] = av.y;
    As[aCol + 2][aRow] = av.z;
    As[aCol + 3][aRow] = av.w;
    float4 bv = *reinterpret_cast<const float4*>(&B[(size_t)(k0 + bRow) * M + colBase + bCol]);
    *reinterpret_cast<float4*>(&Bs[bRow][bCol]) = bv;
    __syncthreads();
#pragma unroll
    for (int kk = 0; kk < 16; ++kk) {
      float a0 = As[kk][ty * 4 + 0], a1 = As[kk][ty * 4 + 1];
      float a2 = As[kk][ty * 4 + 2], a3 = As[kk][ty * 4 + 3];
      float b0 = Bs[kk][tx * 4 + 0], b1 = Bs[kk][tx * 4 + 1];
      float b2 = Bs[kk][tx * 4 + 2], b3 = Bs[kk][tx * 4 + 3];
      c[0][0] += a0 * b0; c[0][1] += a0 * b1; c[0][2] += a0 * b2; c[0][3] += a0 * b3;
      c[1][0] += a1 * b0; c[1][1] += a1 * b1; c[1][2] += a1 * b2; c[1][3] += a1 * b3;
      c[2][0] += a2 * b0; c[2][1] += a2 * b1; c[2][2] += a2 * b2; c[2][3] += a2 * b3;
      c[3][0] += a3 * b0; c[3][1] += a3 * b1; c[3][2] += a3 * b2; c[3][3] += a3 * b3;
    }
    __syncthreads();
  }
#pragma unroll
  for (int i = 0; i < 4; ++i) {
    int row = rowBase + ty * 4 + i;
    if (row < N) {
#pragma unroll
      for (int j = 0; j < 4; ++j) {
        C[(size_t)row * M + colBase + tx * 4 + j] = c[i][j];
      }
    }
  }
}

// ---------------- el/er: per-(node,head) dot of z row with al/ar ----------------
__global__ __launch_bounds__(256) void eler_kernel(const float* __restrict__ z,
                                                   const float* __restrict__ al,
                                                   const float* __restrict__ ar,
                                                   float* __restrict__ el,
                                                   float* __restrict__ er) {
  int wid = (blockIdx.x * 256 + threadIdx.x) >> 6;
  int lane = threadIdx.x & 63;
  if (wid >= NN * NHEAD) return;
  int n = wid >> 2, h = wid & 3;
  const float* zr = z + (size_t)n * HD + h * ND;
  const float* alr = al + h * ND;
  const float* arr = ar + h * ND;
  float z0 = zr[lane], z1 = zr[lane + 64];
  float sl = z0 * alr[lane] + z1 * alr[lane + 64];
  float sr = z0 * arr[lane] + z1 * arr[lane + 64];
  for (int off = 32; off > 0; off >>= 1) {
    sl += __shfl_down(sl, off);
    sr += __shfl_down(sr, off);
  }
  if (lane == 0) { el[wid] = sl; er[wid] = sr; }
}

// ---------------- edge pass: a = exp(leaky_relu(el[src]+er[dst])), denom scatter ----
// NOTE: softmax is shift-invariant; skipping the segment_max is mathematically
// identical (|e| <= ~6 here, no overflow risk in fp32).
__global__ __launch_bounds__(256) void edge_kernel(const int* __restrict__ src,
                                                   const int* __restrict__ dst,
                                                   const float* __restrict__ el,
                                                   const float* __restrict__ er,
                                                   float* __restrict__ a_buf,
                                                   float* __restrict__ denom) {
  int t = blockIdx.x * 256 + threadIdx.x;
  if (t >= NE * NHEAD) return;
  int e = t >> 2, h = t & 3;
  int s = src[e], d = dst[e];
  float x = el[s * NHEAD + h] + er[d * NHEAD + h];
  x = (x > 0.f) ? x : NEG_SLOPE * x;
  float a = expf(x);
  a_buf[t] = a;
  atomicAdd(&denom[d * NHEAD + h], a);
}

// ---------------- aggregation: one wave per (node, head) ----------------
// out[n,h,:] = (sum_e a[e,h] * z[src[e],h,:]) / max(denom,1e-9) + bias
// ELU: layer-1 epilogue. FINAL: fuse head-mean + Wr dot + global sum partials.
template <bool ELU, bool FINAL>
__global__ __launch_bounds__(256) void aggregate_kernel(const float* __restrict__ z,
                                                        const float* __restrict__ a_buf,
                                                        const float* __restrict__ denom,
                                                        const int* __restrict__ offs,
                                                        const int* __restrict__ eids,
                                                        const int* __restrict__ src,
                                                        const float* __restrict__ bias,
                                                        float* __restrict__ out,
                                                        const float* __restrict__ Wr,
                                                        float* __restrict__ partials) {
  __shared__ float blk[4];
  int wid = (blockIdx.x * 256 + threadIdx.x) >> 6;
  int lane = threadIdx.x & 63;
  if (wid < NN * NHEAD) {
    int n = wid >> 2, h = wid & 3;
    int i0 = offs[n], i1 = offs[n + 1];
    float acc0 = 0.f, acc1 = 0.f;
    for (int i = i0; i < i1; ++i) {
      int e = eids[i];
      int s = src[e];
      float a = a_buf[e * NHEAD + h];
      const float* zr = z + (size_t)s * HD + h * ND;
      acc0 += a * zr[lane];
      acc1 += a * zr[lane + 64];
    }
    float dn = denom[n * NHEAD + h];
    float inv = 1.0f / fmaxf(dn, 1e-9f);
    float v0 = acc0 * inv + bias[h * ND + lane];
    float v1 = acc1 * inv + bias[h * ND + 64 + lane];
    if (ELU) {
      v0 = (v0 > 0.f) ? v0 : expm1f(v0);
      v1 = (v1 > 0.f) ? v1 : expm1f(v1);
    }
    if (!FINAL) {
      out[(size_t)n * HD + h * ND + lane] = v0;
      out[(size_t)n * HD + h * ND + 64 + lane] = v1;
    } else {
      float p = 0.25f * (v0 * Wr[lane] + v1 * Wr[lane + 64]);
      for (int off = 32; off > 0; off >>= 1) p += __shfl_down(p, off);
      if (lane == 0) blk[threadIdx.x >> 6] = p;
    }
  } else if (FINAL) {
    if (lane == 0) blk[threadIdx.x >> 6] = 0.f;
  }
  if (FINAL) {
    __syncthreads();
    if (threadIdx.x == 0) {
      float s = blk[0] + blk[1] + blk[2] + blk[3];
      atomicAdd(&partials[blockIdx.x & 255], s);
    }
  }
}

__global__ __launch_bounds__(256) void final_kernel(const float* __restrict__ partials,
                                                    const float* __restrict__ br,
                                                    float* __restrict__ out) {
  __shared__ float tmp[256];
  int t = threadIdx.x;
  tmp[t] = partials[t];
  __syncthreads();
  for (int off = 128; off > 0; off >>= 1) {
    if (t < off) tmp[t] += tmp[t + off];
    __syncthreads();
  }
  if (t == 0) out[0] = tmp[0] + (float)NN * br[0];
}

// ---------------- launch ----------------
extern "C" void kernel_launch(void* const* d_in, const int* in_sizes, int n_in,
                              void* d_out, int out_size, void* d_ws, size_t ws_size,
                              hipStream_t stream) {
  const float* feats = (const float*)d_in[0];
  const int* src = (const int*)d_in[1];
  const int* dst = (const int*)d_in[2];
  const float* W1 = (const float*)d_in[3];
  const float* al1 = (const float*)d_in[4];
  const float* ar1 = (const float*)d_in[5];
  const float* b1 = (const float*)d_in[6];
  const float* W2 = (const float*)d_in[7];
  const float* al2 = (const float*)d_in[8];
  const float* ar2 = (const float*)d_in[9];
  const float* b2 = (const float*)d_in[10];
  const float* Wr = (const float*)d_in[11];
  const float* br = (const float*)d_in[12];
  float* out = (float*)d_out;

  // workspace layout (~89.4 MB total)
  float* z = (float*)d_ws;                       // NN*HD fp32 (z1, then z2)
  float* hbuf = z + (size_t)NN * HD;             // NN*HD fp32 (h1)
  float* a_buf = hbuf + (size_t)NN * HD;         // NE*NHEAD
  float* el = a_buf + (size_t)NE * NHEAD;        // NN*NHEAD
  float* er = el + (size_t)NN * NHEAD;
  float* denom = er + (size_t)NN * NHEAD;
  float* partials = denom + (size_t)NN * NHEAD;  // 256
  int* offs = (int*)(partials + 256);            // NN+1
  int* cursor = offs + (NN + 1);                 // NN
  int* eids = cursor + NN;                       // NE

  // CSR by dst (rebuilt every call; ws is poisoned between calls)
  hipMemsetAsync(cursor, 0, NN * sizeof(int), stream);
  hist_kernel<<<(NE + 255) / 256, 256, 0, stream>>>(dst, cursor);
  scan_kernel<<<1, 1024, 0, stream>>>(cursor, offs);
  copy_kernel<<<(NN + 255) / 256, 256, 0, stream>>>(offs, cursor);
  fill_kernel<<<(NE + 255) / 256, 256, 0, stream>>>(dst, cursor, eids);

  dim3 gemm_grid((NN + 63) / 64, HD / 64);

  // ---- layer 1 ----
  sgemm_kernel<<<gemm_grid, 256, 0, stream>>>(feats, W1, z, NN, 128, HD);
  eler_kernel<<<(NN * NHEAD * 64) / 256, 256, 0, stream>>>(z, al1, ar1, el, er);
  hipMemsetAsync(denom, 0, NN * NHEAD * sizeof(float), stream);
  edge_kernel<<<(NE * NHEAD + 255) / 256, 256, 0, stream>>>(src, dst, el, er, a_buf, denom);
  aggregate_kernel<true, false><<<(NN * NHEAD * 64) / 256, 256, 0, stream>>>(
      z, a_buf, denom, offs, eids, src, b1, hbuf, nullptr, nullptr);

  // ---- layer 2 ----
  sgemm_kernel<<<gemm_grid, 256, 0, stream>>>(hbuf, W2, z, NN, HD, HD);
  eler_kernel<<<(NN * NHEAD * 64) / 256, 256, 0, stream>>>(z, al2, ar2, el, er);
  hipMemsetAsync(denom, 0, NN * NHEAD * sizeof(float), stream);
  edge_kernel<<<(NE * NHEAD + 255) / 256, 256, 0, stream>>>(src, dst, el, er, a_buf, denom);
  hipMemsetAsync(partials, 0, 256 * sizeof(float), stream);
  aggregate_kernel<false, true><<<(NN * NHEAD * 64) / 256, 256, 0, stream>>>(
      z, a_buf, denom, offs, eids, src, b2, nullptr, Wr, partials);
  final_kernel<<<1, 256, 0, stream>>>(partials, br, out);
}

// Round 2
// 475.348 us; speedup vs baseline: 1.5969x; 1.5969x over previous
//
#include <hip/hip_runtime.h>
#include <hip/hip_bf16.h>
#include <cstddef>

// Problem constants (match reference)
constexpr int NN = 20000;   // nodes
constexpr int NE = 320000;  // edges
constexpr int NHEAD = 4;
constexpr int ND = 128;     // per-head dim
constexpr int HD = 512;     // H*D
constexpr float NEG_SLOPE = 0.2f;

// ---------------- CSR build ----------------
__global__ __launch_bounds__(256) void hist_kernel(const int* __restrict__ dst,
                                                   int* __restrict__ cnt) {
  int t = blockIdx.x * 256 + threadIdx.x;
  if (t < NE) atomicAdd(&cnt[dst[t]], 1);
}

// single-block exclusive scan of NN counts -> offs[0..NN]
__global__ __launch_bounds__(1024) void scan_kernel(const int* __restrict__ cnt,
                                                    int* __restrict__ offs) {
  __shared__ int tmp[1024];
  __shared__ int carry_s;
  int t = threadIdx.x;
  if (t == 0) carry_s = 0;
  __syncthreads();
  for (int base = 0; base < NN; base += 1024) {
    int v = (base + t < NN) ? cnt[base + t] : 0;
    tmp[t] = v;
    __syncthreads();
    for (int off = 1; off < 1024; off <<= 1) {
      int x = (t >= off) ? tmp[t - off] : 0;
      __syncthreads();
      tmp[t] += x;
      __syncthreads();
    }
    int incl = tmp[t];
    int carry = carry_s;
    __syncthreads();
    if (base + t < NN) offs[base + t] = carry + incl - v;
    if (t == 1023) carry_s = carry + incl;
    __syncthreads();
  }
  if (t == 0) offs[NN] = carry_s;
}

__global__ __launch_bounds__(256) void copy_kernel(const int* __restrict__ offs,
                                                   int* __restrict__ cursor) {
  int t = blockIdx.x * 256 + threadIdx.x;
  if (t < NN) cursor[t] = offs[t];
}

// Writes src node id directly into CSR slot (no eids indirection later).
__global__ __launch_bounds__(256) void fill_kernel(const int* __restrict__ dst,
                                                   const int* __restrict__ src,
                                                   int* __restrict__ cursor,
                                                   int* __restrict__ src_perm) {
  int t = blockIdx.x * 256 + threadIdx.x;
  if (t < NE) {
    int d = dst[t];
    int p = atomicAdd(&cursor[d], 1);
    src_perm[p] = src[t];
  }
}

// ---------------- fp32 tiled GEMM, bf16 output: C[N,M] = A[N,K] @ B[K,M] ----
// BM=BN=64, BK=16, 256 threads, 4x4 per thread. fp32 accumulate, bf16 store.
__global__ __launch_bounds__(256) void sgemm_kernel(const float* __restrict__ A,
                                                    const float* __restrict__ B,
                                                    __hip_bfloat16* __restrict__ C,
                                                    int N, int K, int M) {
  __shared__ float As[16][65];
  __shared__ float Bs[16][68];
  int t = threadIdx.x;
  int tx = t & 15, ty = t >> 4;
  int rowBase = blockIdx.x * 64;
  int colBase = blockIdx.y * 64;
  float c[4][4] = {};
  int aRow = t >> 2;           // 0..63
  int aCol = (t & 3) * 4;      // 0,4,8,12
  int bRow = t >> 4;           // 0..15
  int bCol = (t & 15) * 4;     // 0..60

  for (int k0 = 0; k0 < K; k0 += 16) {
    float4 av = make_float4(0.f, 0.f, 0.f, 0.f);
    int ar = rowBase + aRow;
    if (ar < N) av = *reinterpret_cast<const float4*>(&A[(size_t)ar * K + k0 + aCol]);
    As[aCol + 0][aRow] = av.x;
    As[aCol + 1][aRow] = av.y;
    As[aCol + 2][aRow] = av.z;
    As[aCol + 3][aRow] = av.w;
    float4 bv = *reinterpret_cast<const float4*>(&B[(size_t)(k0 + bRow) * M + colBase + bCol]);
    *reinterpret_cast<float4*>(&Bs[bRow][bCol]) = bv;
    __syncthreads();
#pragma unroll
    for (int kk = 0; kk < 16; ++kk) {
      float a0 = As[kk][ty * 4 + 0], a1 = As[kk][ty * 4 + 1];
      float a2 = As[kk][ty * 4 + 2], a3 = As[kk][ty * 4 + 3];
      float b0 = Bs[kk][tx * 4 + 0], b1 = Bs[kk][tx * 4 + 1];
      float b2 = Bs[kk][tx * 4 + 2], b3 = Bs[kk][tx * 4 + 3];
      c[0][0] += a0 * b0; c[0][1] += a0 * b1; c[0][2] += a0 * b2; c[0][3] += a0 * b3;
      c[1][0] += a1 * b0; c[1][1] += a1 * b1; c[1][2] += a1 * b2; c[1][3] += a1 * b3;
      c[2][0] += a2 * b0; c[2][1] += a2 * b1; c[2][2] += a2 * b2; c[2][3] += a2 * b3;
      c[3][0] += a3 * b0; c[3][1] += a3 * b1; c[3][2] += a3 * b2; c[3][3] += a3 * b3;
    }
    __syncthreads();
  }
#pragma unroll
  for (int i = 0; i < 4; ++i) {
    int row = rowBase + ty * 4 + i;
    if (row < N) {
#pragma unroll
      for (int j = 0; j < 2; ++j) {
        __hip_bfloat162 p = __float22bfloat162_rn(make_float2(c[i][2 * j], c[i][2 * j + 1]));
        *reinterpret_cast<__hip_bfloat162*>(&C[(size_t)row * M + colBase + tx * 4 + 2 * j]) = p;
      }
    }
  }
}

// ---------------- el/er: per-(node,head) dot of bf16 z row with al/ar --------
__global__ __launch_bounds__(256) void eler_kernel(const __hip_bfloat162* __restrict__ zb,
                                                   const float* __restrict__ al,
                                                   const float* __restrict__ ar,
                                                   float* __restrict__ el,
                                                   float* __restrict__ er) {
  int wid = (blockIdx.x * 256 + threadIdx.x) >> 6;
  int lane = threadIdx.x & 63;
  if (wid >= NN * NHEAD) return;
  int n = wid >> 2, h = wid & 3;
  float2 z = __bfloat1622float2(zb[(size_t)n * 256 + h * 64 + lane]);
  float2 a = *reinterpret_cast<const float2*>(&al[h * ND + 2 * lane]);
  float2 r = *reinterpret_cast<const float2*>(&ar[h * ND + 2 * lane]);
  float sl = z.x * a.x + z.y * a.y;
  float sr = z.x * r.x + z.y * r.y;
  for (int off = 32; off > 0; off >>= 1) {
    sl += __shfl_down(sl, off);
    sr += __shfl_down(sr, off);
  }
  if (lane == 0) { el[wid] = sl; er[wid] = sr; }
}

// ---------------- fused attention + aggregation: one wave per node -----------
// For each incoming edge: a[h] = exp(leaky_relu(el[src][h] + er[n][h]))
// (softmax is shift-invariant; segment_max skipped — |e| is small, no overflow)
// out[n,h,:] = (sum_e a[h] * z[src,h,:]) / max(sum_e a[h], 1e-9) + bias
// Lane l handles elements {2l, 2l+1} of every head. Denominator accumulated
// in-loop (no separate edge pass / atomics).
template <bool ELU, bool FINAL>
__global__ __launch_bounds__(256) void aggregate_kernel(
    const __hip_bfloat162* __restrict__ zb,
    const float* __restrict__ el,
    const float* __restrict__ er,
    const int* __restrict__ offs,
    const int* __restrict__ src_perm,
    const float* __restrict__ bias,
    float2* __restrict__ out,        // viewed as [NN*256] float2
    const float* __restrict__ Wr,
    float* __restrict__ partials) {
  __shared__ float blk[4];
  int n = (blockIdx.x * 256 + threadIdx.x) >> 6;   // grid sized so n < NN always
  int lane = threadIdx.x & 63;
  float4 er4 = *reinterpret_cast<const float4*>(&er[n * 4]);
  int i0 = offs[n], i1 = offs[n + 1];
  float2 acc0 = {0.f, 0.f}, acc1 = {0.f, 0.f}, acc2 = {0.f, 0.f}, acc3 = {0.f, 0.f};
  float4 dsum = {0.f, 0.f, 0.f, 0.f};

#define EDGE_BODY(IDX)                                                         \
  {                                                                            \
    int s = src_perm[IDX];                                                     \
    float4 e4 = *reinterpret_cast<const float4*>(&el[s * 4]);                  \
    float x0 = e4.x + er4.x, x1 = e4.y + er4.y;                                \
    float x2 = e4.z + er4.z, x3 = e4.w + er4.w;                                \
    x0 = (x0 > 0.f) ? x0 : NEG_SLOPE * x0;                                     \
    x1 = (x1 > 0.f) ? x1 : NEG_SLOPE * x1;                                     \
    x2 = (x2 > 0.f) ? x2 : NEG_SLOPE * x2;                                     \
    x3 = (x3 > 0.f) ? x3 : NEG_SLOPE * x3;                                     \
    float a0 = __expf(x0), a1 = __expf(x1), a2 = __expf(x2), a3 = __expf(x3);  \
    dsum.x += a0; dsum.y += a1; dsum.z += a2; dsum.w += a3;                    \
    const __hip_bfloat162* zr = zb + (size_t)s * 256;                          \
    float2 v0 = __bfloat1622float2(zr[lane]);                                  \
    float2 v1 = __bfloat1622float2(zr[64 + lane]);                             \
    float2 v2 = __bfloat1622float2(zr[128 + lane]);                            \
    float2 v3 = __bfloat1622float2(zr[192 + lane]);                            \
    acc0.x += a0 * v0.x; acc0.y += a0 * v0.y;                                  \
    acc1.x += a1 * v1.x; acc1.y += a1 * v1.y;                                  \
    acc2.x += a2 * v2.x; acc2.y += a2 * v2.y;                                  \
    acc3.x += a3 * v3.x; acc3.y += a3 * v3.y;                                  \
  }

  int i = i0;
  for (; i + 1 < i1; i += 2) {
    EDGE_BODY(i)
    EDGE_BODY(i + 1)
  }
  if (i < i1) EDGE_BODY(i)
#undef EDGE_BODY

  float inv0 = 1.0f / fmaxf(dsum.x, 1e-9f);
  float inv1 = 1.0f / fmaxf(dsum.y, 1e-9f);
  float inv2 = 1.0f / fmaxf(dsum.z, 1e-9f);
  float inv3 = 1.0f / fmaxf(dsum.w, 1e-9f);
  float2 b0 = *reinterpret_cast<const float2*>(&bias[0 * ND + 2 * lane]);
  float2 b1 = *reinterpret_cast<const float2*>(&bias[1 * ND + 2 * lane]);
  float2 b2 = *reinterpret_cast<const float2*>(&bias[2 * ND + 2 * lane]);
  float2 b3 = *reinterpret_cast<const float2*>(&bias[3 * ND + 2 * lane]);
  float2 v0 = {acc0.x * inv0 + b0.x, acc0.y * inv0 + b0.y};
  float2 v1 = {acc1.x * inv1 + b1.x, acc1.y * inv1 + b1.y};
  float2 v2 = {acc2.x * inv2 + b2.x, acc2.y * inv2 + b2.y};
  float2 v3 = {acc3.x * inv3 + b3.x, acc3.y * inv3 + b3.y};
  if (ELU) {
    v0.x = (v0.x > 0.f) ? v0.x : expm1f(v0.x);
    v0.y = (v0.y > 0.f) ? v0.y : expm1f(v0.y);
    v1.x = (v1.x > 0.f) ? v1.x : expm1f(v1.x);
    v1.y = (v1.y > 0.f) ? v1.y : expm1f(v1.y);
    v2.x = (v2.x > 0.f) ? v2.x : expm1f(v2.x);
    v2.y = (v2.y > 0.f) ? v2.y : expm1f(v2.y);
    v3.x = (v3.x > 0.f) ? v3.x : expm1f(v3.x);
    v3.y = (v3.y > 0.f) ? v3.y : expm1f(v3.y);
  }
  if (!FINAL) {
    float2* o = out + (size_t)n * 256;
    o[lane] = v0;
    o[64 + lane] = v1;
    o[128 + lane] = v2;
    o[192 + lane] = v3;
  } else {
    float2 wr = *reinterpret_cast<const float2*>(&Wr[2 * lane]);
    float p = 0.25f * ((v0.x + v1.x + v2.x + v3.x) * wr.x +
                       (v0.y + v1.y + v2.y + v3.y) * wr.y);
    for (int off = 32; off > 0; off >>= 1) p += __shfl_down(p, off);
    if (lane == 0) blk[threadIdx.x >> 6] = p;
    __syncthreads();
    if (threadIdx.x == 0) {
      float s = blk[0] + blk[1] + blk[2] + blk[3];
      atomicAdd(&partials[blockIdx.x & 255], s);
    }
  }
}

__global__ __launch_bounds__(256) void final_kernel(const float* __restrict__ partials,
                                                    const float* __restrict__ br,
                                                    float* __restrict__ out) {
  __shared__ float tmp[256];
  int t = threadIdx.x;
  tmp[t] = partials[t];
  __syncthreads();
  for (int off = 128; off > 0; off >>= 1) {
    if (t < off) tmp[t] += tmp[t + off];
    __syncthreads();
  }
  if (t == 0) out[0] = tmp[0] + (float)NN * br[0];
}

// ---------------- launch ----------------
extern "C" void kernel_launch(void* const* d_in, const int* in_sizes, int n_in,
                              void* d_out, int out_size, void* d_ws, size_t ws_size,
                              hipStream_t stream) {
  const float* feats = (const float*)d_in[0];
  const int* src = (const int*)d_in[1];
  const int* dst = (const int*)d_in[2];
  const float* W1 = (const float*)d_in[3];
  const float* al1 = (const float*)d_in[4];
  const float* ar1 = (const float*)d_in[5];
  const float* b1 = (const float*)d_in[6];
  const float* W2 = (const float*)d_in[7];
  const float* al2 = (const float*)d_in[8];
  const float* ar2 = (const float*)d_in[9];
  const float* b2 = (const float*)d_in[10];
  const float* Wr = (const float*)d_in[11];
  const float* br = (const float*)d_in[12];
  float* out = (float*)d_out;

  // workspace layout (~64 MB)
  __hip_bfloat16* zb = (__hip_bfloat16*)d_ws;          // NN*HD bf16 (z1, then z2)
  float* hbuf = (float*)(zb + (size_t)NN * HD);        // NN*HD fp32 (h1)
  float* el = hbuf + (size_t)NN * HD;                  // NN*4
  float* er = el + (size_t)NN * NHEAD;                 // NN*4
  float* partials = er + (size_t)NN * NHEAD;           // 256
  int* offs = (int*)(partials + 256);                  // NN+1
  int* cursor = offs + (NN + 1);                       // NN
  int* src_perm = cursor + NN;                         // NE

  // CSR by dst (rebuilt every call; ws is poisoned between calls)
  hipMemsetAsync(cursor, 0, NN * sizeof(int), stream);
  hist_kernel<<<(NE + 255) / 256, 256, 0, stream>>>(dst, cursor);
  scan_kernel<<<1, 1024, 0, stream>>>(cursor, offs);
  copy_kernel<<<(NN + 255) / 256, 256, 0, stream>>>(offs, cursor);
  fill_kernel<<<(NE + 255) / 256, 256, 0, stream>>>(dst, src, cursor, src_perm);

  dim3 gemm_grid((NN + 63) / 64, HD / 64);
  const __hip_bfloat162* zb2 = (const __hip_bfloat162*)zb;

  // ---- layer 1 ----
  sgemm_kernel<<<gemm_grid, 256, 0, stream>>>(feats, W1, zb, NN, 128, HD);
  eler_kernel<<<(NN * NHEAD * 64) / 256, 256, 0, stream>>>(zb2, al1, ar1, el, er);
  aggregate_kernel<true, false><<<(NN * 64) / 256, 256, 0, stream>>>(
      zb2, el, er, offs, src_perm, b1, (float2*)hbuf, nullptr, nullptr);

  // ---- layer 2 ----
  sgemm_kernel<<<gemm_grid, 256, 0, stream>>>(hbuf, W2, zb, NN, HD, HD);
  eler_kernel<<<(NN * NHEAD * 64) / 256, 256, 0, stream>>>(zb2, al2, ar2, el, er);
  hipMemsetAsync(partials, 0, 256 * sizeof(float), stream);
  aggregate_kernel<false, true><<<(NN * 64) / 256, 256, 0, stream>>>(
      zb2, el, er, offs, src_perm, b2, nullptr, Wr, partials);
  final_kernel<<<1, 256, 0, stream>>>(partials, br, out);
}

// Round 3
// 326.142 us; speedup vs baseline: 2.3274x; 1.4575x over previous
//
#include <hip/hip_runtime.h>
#include <hip/hip_bf16.h>
#include <cstddef>

// Problem constants (match reference)
constexpr int NN = 20000;   // nodes
constexpr int NE = 320000;  // edges
constexpr int NHEAD = 4;
constexpr int ND = 128;     // per-head dim
constexpr int HD = 512;     // H*D
constexpr int MPAD = 20096; // 157 * 128, padded row count for GEMM tiles
constexpr float NEG_SLOPE = 0.2f;

using short8 = __attribute__((ext_vector_type(8))) short;
using f32x4 = __attribute__((ext_vector_type(4))) float;

// async global->LDS, 16B per lane, LDS dest = wave-uniform base + lane*16
__device__ inline void gload16(const void* g, void* l) {
  __builtin_amdgcn_global_load_lds(
      (const __attribute__((address_space(1))) void*)g,
      (__attribute__((address_space(3))) void*)l, 16, 0, 0);
}

// ---------------- CSR build ----------------
__global__ __launch_bounds__(256) void hist_kernel(const int* __restrict__ dst,
                                                   int* __restrict__ cnt) {
  int t = blockIdx.x * 256 + threadIdx.x;
  if (t < NE) atomicAdd(&cnt[dst[t]], 1);
}

// single-block exclusive scan of NN counts -> offs[0..NN]
__global__ __launch_bounds__(1024) void scan_kernel(const int* __restrict__ cnt,
                                                    int* __restrict__ offs) {
  __shared__ int tmp[1024];
  __shared__ int carry_s;
  int t = threadIdx.x;
  if (t == 0) carry_s = 0;
  __syncthreads();
  for (int base = 0; base < NN; base += 1024) {
    int v = (base + t < NN) ? cnt[base + t] : 0;
    tmp[t] = v;
    __syncthreads();
    for (int off = 1; off < 1024; off <<= 1) {
      int x = (t >= off) ? tmp[t - off] : 0;
      __syncthreads();
      tmp[t] += x;
      __syncthreads();
    }
    int incl = tmp[t];
    int carry = carry_s;
    __syncthreads();
    if (base + t < NN) offs[base + t] = carry + incl - v;
    if (t == 1023) carry_s = carry + incl;
    __syncthreads();
  }
  if (t == 0) offs[NN] = carry_s;
}

__global__ __launch_bounds__(256) void copy_kernel(const int* __restrict__ offs,
                                                   int* __restrict__ cursor) {
  int t = blockIdx.x * 256 + threadIdx.x;
  if (t < NN) cursor[t] = offs[t];
}

// Writes src node id directly into CSR slot (no eids indirection later).
__global__ __launch_bounds__(256) void fill_kernel(const int* __restrict__ dst,
                                                   const int* __restrict__ src,
                                                   int* __restrict__ cursor,
                                                   int* __restrict__ src_perm) {
  int t = blockIdx.x * 256 + threadIdx.x;
  if (t < NE) {
    int d = dst[t];
    int p = atomicAdd(&cursor[d], 1);
    src_perm[p] = src[t];
  }
}

// ---------------- dtype prep ----------------
// fp32 -> bf16, zero-padding past n_valid
__global__ __launch_bounds__(256) void tobf16_pad_kernel(const float* __restrict__ X,
                                                         __hip_bfloat16* __restrict__ Y,
                                                         int n_valid, int n_total) {
  int t = blockIdx.x * 256 + threadIdx.x;
  if (t >= n_total) return;
  Y[t] = __float2bfloat16(t < n_valid ? X[t] : 0.f);
}

// W [K][M] fp32 -> Wt [M][K] bf16
__global__ __launch_bounds__(256) void transpose_bf16_kernel(const float* __restrict__ W,
                                                             __hip_bfloat16* __restrict__ Wt,
                                                             int K, int M) {
  int t = blockIdx.x * 256 + threadIdx.x;
  if (t >= K * M) return;
  int m = t / K, k = t - m * K;
  Wt[t] = __float2bfloat16(W[(size_t)k * M + m]);
}

// ---------------- bf16 MFMA GEMM: C[Mpad][N] = A[Mpad][K] @ Bt[N][K]^T ------
// 128x128 tile, 256 threads = 4 waves, each wave 64x64 via 4x4 mfma_16x16x32.
// A, Bt staged to LDS with global_load_lds width=16. No bounds checks: caller
// guarantees Mpad multiple of 128 and N multiple of 128.
__global__ __launch_bounds__(256) void mfma_gemm_kernel(
    const __hip_bfloat16* __restrict__ A,   // [Mpad][K] bf16 row-major
    const __hip_bfloat16* __restrict__ Bt,  // [N][K] bf16 row-major (B^T)
    __hip_bfloat16* __restrict__ C,         // [Mpad][N]
    int K, int N) {
  __shared__ short As[128 * 32];
  __shared__ short Bs[128 * 32];
  int t = threadIdx.x;
  int lane = t & 63;
  int wave = t >> 6;
  int rowBase = blockIdx.x * 128;
  int colBase = blockIdx.y * 128;
  int woffr = (wave & 1) * 64;
  int woffc = (wave >> 1) * 64;
  int mrow = lane & 15, quad = lane >> 4;

  f32x4 acc[4][4];
#pragma unroll
  for (int i = 0; i < 4; ++i)
#pragma unroll
    for (int j = 0; j < 4; ++j) acc[i][j] = (f32x4){0.f, 0.f, 0.f, 0.f};

  for (int k0 = 0; k0 < K; k0 += 32) {
    // stage A tile [128][32] and Bt tile [128][32]; chunk f = 16B = (row f/4, k-chunk f%4)
#pragma unroll
    for (int p = 0; p < 2; ++p) {
      int f = p * 256 + wave * 64 + lane;
      int r = f >> 2, kc = f & 3;
      gload16(A + (size_t)(rowBase + r) * K + k0 + kc * 8,
              As + p * 2048 + wave * 512);
      gload16(Bt + (size_t)(colBase + r) * K + k0 + kc * 8,
              Bs + p * 2048 + wave * 512);
    }
    __syncthreads();
    short8 af[4], bfr[4];
#pragma unroll
    for (int i = 0; i < 4; ++i)
      af[i] = *(const short8*)&As[(woffr + i * 16 + mrow) * 32 + quad * 8];
#pragma unroll
    for (int j = 0; j < 4; ++j)
      bfr[j] = *(const short8*)&Bs[(woffc + j * 16 + mrow) * 32 + quad * 8];
#pragma unroll
    for (int i = 0; i < 4; ++i)
#pragma unroll
      for (int j = 0; j < 4; ++j)
        acc[i][j] = __builtin_amdgcn_mfma_f32_16x16x32_bf16(af[i], bfr[j], acc[i][j], 0, 0, 0);
    __syncthreads();
  }

  // C/D layout: col = lane&15, row = quad*4 + reg (verified m89/m91)
#pragma unroll
  for (int i = 0; i < 4; ++i) {
#pragma unroll
    for (int j = 0; j < 4; ++j) {
      int col = colBase + woffc + j * 16 + mrow;
#pragma unroll
      for (int r = 0; r < 4; ++r) {
        int row = rowBase + woffr + i * 16 + quad * 4 + r;
        C[(size_t)row * N + col] = __float2bfloat16(acc[i][j][r]);
      }
    }
  }
}

// ---------------- el/er: per-(node,head) dot of bf16 z row with al/ar --------
__global__ __launch_bounds__(256) void eler_kernel(const __hip_bfloat162* __restrict__ zb,
                                                   const float* __restrict__ al,
                                                   const float* __restrict__ ar,
                                                   float* __restrict__ el,
                                                   float* __restrict__ er) {
  int wid = (blockIdx.x * 256 + threadIdx.x) >> 6;
  int lane = threadIdx.x & 63;
  if (wid >= NN * NHEAD) return;
  int n = wid >> 2, h = wid & 3;
  float2 z = __bfloat1622float2(zb[(size_t)n * 256 + h * 64 + lane]);
  float2 a = *reinterpret_cast<const float2*>(&al[h * ND + 2 * lane]);
  float2 r = *reinterpret_cast<const float2*>(&ar[h * ND + 2 * lane]);
  float sl = z.x * a.x + z.y * a.y;
  float sr = z.x * r.x + z.y * r.y;
  for (int off = 32; off > 0; off >>= 1) {
    sl += __shfl_down(sl, off);
    sr += __shfl_down(sr, off);
  }
  if (lane == 0) { el[wid] = sl; er[wid] = sr; }
}

// ---------------- fused attention + aggregation: one wave per node -----------
// a[h] = exp(leaky_relu(el[src][h] + er[n][h])) (softmax shift-invariance ->
// segment_max skipped; |e| small, no overflow). Denominator in-loop.
// out[n,h,:] = (sum a*z)/max(sum a,1e-9) + bias; ELU for layer 1 (bf16 out),
// FINAL fuses head-mean + Wr dot + global-sum partials for layer 2.
template <bool ELU, bool FINAL>
__global__ __launch_bounds__(256) void aggregate_kernel(
    const __hip_bfloat162* __restrict__ zb,
    const float* __restrict__ el,
    const float* __restrict__ er,
    const int* __restrict__ offs,
    const int* __restrict__ src_perm,
    const float* __restrict__ bias,
    __hip_bfloat162* __restrict__ out,   // [NN*256] bf162 (layer-1 h)
    const float* __restrict__ Wr,
    float* __restrict__ partials) {
  __shared__ float blk[4];
  int n = (blockIdx.x * 256 + threadIdx.x) >> 6;   // grid sized so n < NN always
  int lane = threadIdx.x & 63;
  float4 er4 = *reinterpret_cast<const float4*>(&er[n * 4]);
  int i0 = offs[n], i1 = offs[n + 1];
  float2 acc0 = {0.f, 0.f}, acc1 = {0.f, 0.f}, acc2 = {0.f, 0.f}, acc3 = {0.f, 0.f};
  float4 dsum = {0.f, 0.f, 0.f, 0.f};

#define EDGE_BODY(IDX)                                                         \
  {                                                                            \
    int s = src_perm[IDX];                                                     \
    float4 e4 = *reinterpret_cast<const float4*>(&el[s * 4]);                  \
    float x0 = e4.x + er4.x, x1 = e4.y + er4.y;                                \
    float x2 = e4.z + er4.z, x3 = e4.w + er4.w;                                \
    x0 = (x0 > 0.f) ? x0 : NEG_SLOPE * x0;                                     \
    x1 = (x1 > 0.f) ? x1 : NEG_SLOPE * x1;                                     \
    x2 = (x2 > 0.f) ? x2 : NEG_SLOPE * x2;                                     \
    x3 = (x3 > 0.f) ? x3 : NEG_SLOPE * x3;                                     \
    float a0 = __expf(x0), a1 = __expf(x1), a2 = __expf(x2), a3 = __expf(x3);  \
    dsum.x += a0; dsum.y += a1; dsum.z += a2; dsum.w += a3;                    \
    const __hip_bfloat162* zr = zb + (size_t)s * 256;                          \
    float2 v0 = __bfloat1622float2(zr[lane]);                                  \
    float2 v1 = __bfloat1622float2(zr[64 + lane]);                             \
    float2 v2 = __bfloat1622float2(zr[128 + lane]);                            \
    float2 v3 = __bfloat1622float2(zr[192 + lane]);                            \
    acc0.x += a0 * v0.x; acc0.y += a0 * v0.y;                                  \
    acc1.x += a1 * v1.x; acc1.y += a1 * v1.y;                                  \
    acc2.x += a2 * v2.x; acc2.y += a2 * v2.y;                                  \
    acc3.x += a3 * v3.x; acc3.y += a3 * v3.y;                                  \
  }

  int i = i0;
  for (; i + 1 < i1; i += 2) {
    EDGE_BODY(i)
    EDGE_BODY(i + 1)
  }
  if (i < i1) EDGE_BODY(i)
#undef EDGE_BODY

  float inv0 = 1.0f / fmaxf(dsum.x, 1e-9f);
  float inv1 = 1.0f / fmaxf(dsum.y, 1e-9f);
  float inv2 = 1.0f / fmaxf(dsum.z, 1e-9f);
  float inv3 = 1.0f / fmaxf(dsum.w, 1e-9f);
  float2 b0 = *reinterpret_cast<const float2*>(&bias[0 * ND + 2 * lane]);
  float2 b1 = *reinterpret_cast<const float2*>(&bias[1 * ND + 2 * lane]);
  float2 b2 = *reinterpret_cast<const float2*>(&bias[2 * ND + 2 * lane]);
  float2 b3 = *reinterpret_cast<const float2*>(&bias[3 * ND + 2 * lane]);
  float2 v0 = {acc0.x * inv0 + b0.x, acc0.y * inv0 + b0.y};
  float2 v1 = {acc1.x * inv1 + b1.x, acc1.y * inv1 + b1.y};
  float2 v2 = {acc2.x * inv2 + b2.x, acc2.y * inv2 + b2.y};
  float2 v3 = {acc3.x * inv3 + b3.x, acc3.y * inv3 + b3.y};
  if (ELU) {
    v0.x = (v0.x > 0.f) ? v0.x : expm1f(v0.x);
    v0.y = (v0.y > 0.f) ? v0.y : expm1f(v0.y);
    v1.x = (v1.x > 0.f) ? v1.x : expm1f(v1.x);
    v1.y = (v1.y > 0.f) ? v1.y : expm1f(v1.y);
    v2.x = (v2.x > 0.f) ? v2.x : expm1f(v2.x);
    v2.y = (v2.y > 0.f) ? v2.y : expm1f(v2.y);
    v3.x = (v3.x > 0.f) ? v3.x : expm1f(v3.x);
    v3.y = (v3.y > 0.f) ? v3.y : expm1f(v3.y);
  }
  if (!FINAL) {
    __hip_bfloat162* o = out + (size_t)n * 256;
    o[lane] = __float22bfloat162_rn(make_float2(v0.x, v0.y));
    o[64 + lane] = __float22bfloat162_rn(make_float2(v1.x, v1.y));
    o[128 + lane] = __float22bfloat162_rn(make_float2(v2.x, v2.y));
    o[192 + lane] = __float22bfloat162_rn(make_float2(v3.x, v3.y));
  } else {
    float2 wr = *reinterpret_cast<const float2*>(&Wr[2 * lane]);
    float p = 0.25f * ((v0.x + v1.x + v2.x + v3.x) * wr.x +
                       (v0.y + v1.y + v2.y + v3.y) * wr.y);
    for (int off = 32; off > 0; off >>= 1) p += __shfl_down(p, off);
    if (lane == 0) blk[threadIdx.x >> 6] = p;
    __syncthreads();
    if (threadIdx.x == 0) {
      float s = blk[0] + blk[1] + blk[2] + blk[3];
      atomicAdd(&partials[blockIdx.x & 255], s);
    }
  }
}

__global__ __launch_bounds__(256) void final_kernel(const float* __restrict__ partials,
                                                    const float* __restrict__ br,
                                                    float* __restrict__ out) {
  __shared__ float tmp[256];
  int t = threadIdx.x;
  tmp[t] = partials[t];
  __syncthreads();
  for (int off = 128; off > 0; off >>= 1) {
    if (t < off) tmp[t] += tmp[t + off];
    __syncthreads();
  }
  if (t == 0) out[0] = tmp[0] + (float)NN * br[0];
}

// ---------------- launch ----------------
extern "C" void kernel_launch(void* const* d_in, const int* in_sizes, int n_in,
                              void* d_out, int out_size, void* d_ws, size_t ws_size,
                              hipStream_t stream) {
  const float* feats = (const float*)d_in[0];
  const int* src = (const int*)d_in[1];
  const int* dst = (const int*)d_in[2];
  const float* W1 = (const float*)d_in[3];
  const float* al1 = (const float*)d_in[4];
  const float* ar1 = (const float*)d_in[5];
  const float* b1 = (const float*)d_in[6];
  const float* W2 = (const float*)d_in[7];
  const float* al2 = (const float*)d_in[8];
  const float* ar2 = (const float*)d_in[9];
  const float* b2 = (const float*)d_in[10];
  const float* Wr = (const float*)d_in[11];
  const float* br = (const float*)d_in[12];
  float* out = (float*)d_out;

  // workspace layout (~48 MB); all section sizes multiples of 16 B
  __hip_bfloat16* featsb = (__hip_bfloat16*)d_ws;       // MPAD*128 bf16
  __hip_bfloat16* zb = featsb + (size_t)MPAD * 128;     // MPAD*HD bf16 (z1, then z2)
  __hip_bfloat16* hb = zb + (size_t)MPAD * HD;          // MPAD*HD bf16 (h1)
  __hip_bfloat16* W1t = hb + (size_t)MPAD * HD;         // 512*128 bf16
  __hip_bfloat16* W2t = W1t + 512 * 128;                // 512*512 bf16
  float* el = (float*)(W2t + 512 * 512);                // NN*4
  float* er = el + (size_t)NN * NHEAD;                  // NN*4
  float* partials = er + (size_t)NN * NHEAD;            // 256
  int* offs = (int*)(partials + 256);                   // NN+1
  int* cursor = offs + (NN + 1);                        // NN
  int* src_perm = cursor + NN;                          // NE

  // CSR by dst (rebuilt every call; ws is poisoned between calls)
  hipMemsetAsync(cursor, 0, NN * sizeof(int), stream);
  hist_kernel<<<(NE + 255) / 256, 256, 0, stream>>>(dst, cursor);
  scan_kernel<<<1, 1024, 0, stream>>>(cursor, offs);
  copy_kernel<<<(NN + 255) / 256, 256, 0, stream>>>(offs, cursor);
  fill_kernel<<<(NE + 255) / 256, 256, 0, stream>>>(dst, src, cursor, src_perm);

  // dtype prep
  tobf16_pad_kernel<<<(MPAD * 128 + 255) / 256, 256, 0, stream>>>(
      feats, featsb, NN * 128, MPAD * 128);
  transpose_bf16_kernel<<<(128 * 512 + 255) / 256, 256, 0, stream>>>(W1, W1t, 128, 512);
  transpose_bf16_kernel<<<(512 * 512 + 255) / 256, 256, 0, stream>>>(W2, W2t, 512, 512);

  dim3 gemm_grid(MPAD / 128, HD / 128);
  const __hip_bfloat162* zb2 = (const __hip_bfloat162*)zb;

  // ---- layer 1 ----
  mfma_gemm_kernel<<<gemm_grid, 256, 0, stream>>>(featsb, W1t, zb, 128, HD);
  eler_kernel<<<(NN * NHEAD * 64) / 256, 256, 0, stream>>>(zb2, al1, ar1, el, er);
  aggregate_kernel<true, false><<<(NN * 64) / 256, 256, 0, stream>>>(
      zb2, el, er, offs, src_perm, b1, (__hip_bfloat162*)hb, nullptr, nullptr);

  // ---- layer 2 ----
  mfma_gemm_kernel<<<gemm_grid, 256, 0, stream>>>(hb, W2t, zb, HD, HD);
  eler_kernel<<<(NN * NHEAD * 64) / 256, 256, 0, stream>>>(zb2, al2, ar2, el, er);
  hipMemsetAsync(partials, 0, 256 * sizeof(float), stream);
  aggregate_kernel<false, true><<<(NN * 64) / 256, 256, 0, stream>>>(
      zb2, el, er, offs, src_perm, b2, nullptr, Wr, partials);
  final_kernel<<<1, 256, 0, stream>>>(partials, br, out);
}

// Round 4
// 261.138 us; speedup vs baseline: 2.9068x; 1.2489x over previous
//
#include <hip/hip_runtime.h>
#include <hip/hip_bf16.h>
#include <cstddef>

// Problem constants (match reference)
constexpr int NN = 20000;   // nodes
constexpr int NE = 320000;  // edges
constexpr int NHEAD = 4;
constexpr int ND = 128;     // per-head dim
constexpr int HD = 512;     // H*D
constexpr int MPAD = 20096; // 157 * 128, padded row count for GEMM tiles
constexpr int SLOTS = 64;   // padded-CSR slots per node (Poisson(16): P(>64)~1e-20)
constexpr float NEG_SLOPE = 0.2f;

using short8 = __attribute__((ext_vector_type(8))) short;
using f32x4 = __attribute__((ext_vector_type(4))) float;

// async global->LDS, 16B per lane, LDS dest = wave-uniform base + lane*16
__device__ inline void gload16(const void* g, void* l) {
  __builtin_amdgcn_global_load_lds(
      (const __attribute__((address_space(1))) void*)g,
      (__attribute__((address_space(3))) void*)l, 16, 0, 0);
}

// ---------------- padded-CSR fill: src_perm[d*64+p] = src, cnt via atomics ---
__global__ __launch_bounds__(256) void fill_kernel(const int* __restrict__ dst,
                                                   const int* __restrict__ src,
                                                   int* __restrict__ cnt,
                                                   int* __restrict__ src_perm) {
  int t = blockIdx.x * 256 + threadIdx.x;
  if (t < NE) {
    int d = dst[t];
    int p = atomicAdd(&cnt[d], 1);
    if (p < SLOTS) src_perm[d * SLOTS + p] = src[t];
  }
}

// ---------------- dtype prep ----------------
// fp32 -> bf16, zero-padding past n_valid
__global__ __launch_bounds__(256) void tobf16_pad_kernel(const float* __restrict__ X,
                                                         __hip_bfloat16* __restrict__ Y,
                                                         int n_valid, int n_total) {
  int t = blockIdx.x * 256 + threadIdx.x;
  if (t >= n_total) return;
  Y[t] = __float2bfloat16(t < n_valid ? X[t] : 0.f);
}

// W [K][M] fp32 -> Wt [M][K] bf16
__global__ __launch_bounds__(256) void transpose_bf16_kernel(const float* __restrict__ W,
                                                             __hip_bfloat16* __restrict__ Wt,
                                                             int K, int M) {
  int t = blockIdx.x * 256 + threadIdx.x;
  if (t >= K * M) return;
  int m = t / K, k = t - m * K;
  Wt[t] = __float2bfloat16(W[(size_t)k * M + m]);
}

// ---------------- bf16 MFMA GEMM + fused el/er epilogue ---------------------
// C[Mpad][512] = A[Mpad][K] @ Bt[512][K]^T.  128x128 tile, 256 threads = 4
// waves, each 64x64 via 4x4 mfma_16x16x32.  blockIdx.y = head (D=128 = tile
// width), so each block also reduces el/er = z . al/ar for its 128 rows and
// stores them directly (eler kernel eliminated).
__global__ __launch_bounds__(256) void mfma_gemm_kernel(
    const __hip_bfloat16* __restrict__ A,   // [Mpad][K] bf16 row-major
    const __hip_bfloat16* __restrict__ Bt,  // [512][K] bf16 row-major (B^T)
    __hip_bfloat16* __restrict__ C,         // [Mpad][512]
    int K,
    const float* __restrict__ al,           // [4][128]
    const float* __restrict__ ar,           // [4][128]
    float* __restrict__ el,                 // [NN][4]
    float* __restrict__ er) {               // [NN][4]
  __shared__ short As[128 * 32];
  __shared__ short Bs[128 * 32];
  __shared__ float elbuf[4][128];
  __shared__ float erbuf[4][128];
  int t = threadIdx.x;
  int lane = t & 63;
  int wave = t >> 6;
  int rowBase = blockIdx.x * 128;
  int head = blockIdx.y;
  int colBase = head * 128;
  int woffr = (wave & 1) * 64;
  int woffc = (wave >> 1) * 64;
  int mrow = lane & 15, quad = lane >> 4;

  f32x4 acc[4][4];
#pragma unroll
  for (int i = 0; i < 4; ++i)
#pragma unroll
    for (int j = 0; j < 4; ++j) acc[i][j] = (f32x4){0.f, 0.f, 0.f, 0.f};

  for (int k0 = 0; k0 < K; k0 += 32) {
    // stage A tile [128][32] and Bt tile [128][32]; chunk f = (row f/4, k-chunk f%4)
#pragma unroll
    for (int p = 0; p < 2; ++p) {
      int f = p * 256 + wave * 64 + lane;
      int r = f >> 2, kc = f & 3;
      gload16(A + (size_t)(rowBase + r) * K + k0 + kc * 8,
              As + p * 2048 + wave * 512);
      gload16(Bt + (size_t)(colBase + r) * K + k0 + kc * 8,
              Bs + p * 2048 + wave * 512);
    }
    __syncthreads();
    short8 af[4], bfr[4];
#pragma unroll
    for (int i = 0; i < 4; ++i)
      af[i] = *(const short8*)&As[(woffr + i * 16 + mrow) * 32 + quad * 8];
#pragma unroll
    for (int j = 0; j < 4; ++j)
      bfr[j] = *(const short8*)&Bs[(woffc + j * 16 + mrow) * 32 + quad * 8];
#pragma unroll
    for (int i = 0; i < 4; ++i)
#pragma unroll
      for (int j = 0; j < 4; ++j)
        acc[i][j] = __builtin_amdgcn_mfma_f32_16x16x32_bf16(af[i], bfr[j], acc[i][j], 0, 0, 0);
    __syncthreads();
  }

  // C store. C/D layout: col = lane&15, row = quad*4 + reg (verified m89/m91)
#pragma unroll
  for (int i = 0; i < 4; ++i) {
#pragma unroll
    for (int j = 0; j < 4; ++j) {
      int col = colBase + woffc + j * 16 + mrow;
#pragma unroll
      for (int r = 0; r < 4; ++r) {
        int row = rowBase + woffr + i * 16 + quad * 4 + r;
        C[(size_t)row * HD + col] = __float2bfloat16(acc[i][j][r]);
      }
    }
  }

  // ---- fused el/er epilogue: el[row] = sum_col z[row,col]*al[head,col] ----
  float al_v[4], ar_v[4];
#pragma unroll
  for (int j = 0; j < 4; ++j) {
    int coll = woffc + j * 16 + mrow;
    al_v[j] = al[head * 128 + coll];
    ar_v[j] = ar[head * 128 + coll];
  }
#pragma unroll
  for (int i = 0; i < 4; ++i) {
#pragma unroll
    for (int r = 0; r < 4; ++r) {
      float pl = 0.f, pr = 0.f;
#pragma unroll
      for (int j = 0; j < 4; ++j) {
        float v = acc[i][j][r];
        pl += v * al_v[j];
        pr += v * ar_v[j];
      }
      // reduce over the 16 lanes (mrow) that share this row (xor stays in quad group)
#pragma unroll
      for (int off = 1; off < 16; off <<= 1) {
        pl += __shfl_xor(pl, off);
        pr += __shfl_xor(pr, off);
      }
      if (mrow == 0) {
        int row128 = woffr + i * 16 + quad * 4 + r;
        elbuf[wave][row128] = pl;
        erbuf[wave][row128] = pr;
      }
    }
  }
  __syncthreads();
  // waves (0: rows0-63/cols0-63, 1: rows64-127/cols0-63, 2: rows0-63/cols64-127,
  //        3: rows64-127/cols64-127) -> combine col halves
  if (t < 128) {
    int row = t;
    float ev, rv;
    if (row < 64) { ev = elbuf[0][row] + elbuf[2][row]; rv = erbuf[0][row] + erbuf[2][row]; }
    else          { ev = elbuf[1][row] + elbuf[3][row]; rv = erbuf[1][row] + erbuf[3][row]; }
    int gr = rowBase + row;
    if (gr < NN) {
      el[gr * 4 + head] = ev;
      er[gr * 4 + head] = rv;
    }
  }
}

// ---------------- per-node attention: one wave per node, lane = slot ---------
// a = exp(leaky_relu(el[src]+er[n])) (softmax shift-invariance -> segment_max
// skipped; |e| small). Wave-reduce denom, store pre-normalized alpha (fp32).
__global__ __launch_bounds__(256) void attn_kernel(const int* __restrict__ src_perm,
                                                   const int* __restrict__ cnt,
                                                   const float* __restrict__ el,
                                                   const float* __restrict__ er,
                                                   float4* __restrict__ a_perm) {
  int wv = __builtin_amdgcn_readfirstlane((int)(threadIdx.x >> 6));
  int n = blockIdx.x * 4 + wv;
  int lane = threadIdx.x & 63;
  int c = min(cnt[n], SLOTS);
  float4 er4 = *reinterpret_cast<const float4*>(&er[n * 4]);
  float a0 = 0.f, a1 = 0.f, a2 = 0.f, a3 = 0.f;
  bool act = lane < c;
  if (act) {
    int s = src_perm[n * SLOTS + lane];
    float4 e4 = *reinterpret_cast<const float4*>(&el[s * 4]);
    float x0 = e4.x + er4.x, x1 = e4.y + er4.y;
    float x2 = e4.z + er4.z, x3 = e4.w + er4.w;
    x0 = (x0 > 0.f) ? x0 : NEG_SLOPE * x0;
    x1 = (x1 > 0.f) ? x1 : NEG_SLOPE * x1;
    x2 = (x2 > 0.f) ? x2 : NEG_SLOPE * x2;
    x3 = (x3 > 0.f) ? x3 : NEG_SLOPE * x3;
    a0 = __expf(x0); a1 = __expf(x1); a2 = __expf(x2); a3 = __expf(x3);
  }
  float s0 = a0, s1 = a1, s2 = a2, s3 = a3;
#pragma unroll
  for (int off = 1; off < 64; off <<= 1) {
    s0 += __shfl_xor(s0, off);
    s1 += __shfl_xor(s1, off);
    s2 += __shfl_xor(s2, off);
    s3 += __shfl_xor(s3, off);
  }
  if (act) {
    float4 r;
    r.x = a0 / fmaxf(s0, 1e-9f);
    r.y = a1 / fmaxf(s1, 1e-9f);
    r.z = a2 / fmaxf(s2, 1e-9f);
    r.w = a3 / fmaxf(s3, 1e-9f);
    a_perm[n * SLOTS + lane] = r;
  }
}

// ---------------- aggregation: one wave per node, pre-normalized alpha -------
// out[n,h,:] = sum_e alpha[e,h] * z[src,h,:] + bias.  alpha/src loads are
// wave-uniform (scalar); only z rows are random gathers.
template <bool ELU, bool FINAL>
__global__ __launch_bounds__(256) void aggregate_kernel(
    const __hip_bfloat162* __restrict__ zb,
    const float4* __restrict__ a_perm,
    const int* __restrict__ cnt,
    const int* __restrict__ src_perm,
    const float* __restrict__ bias,
    __hip_bfloat162* __restrict__ out,   // [NN*256] bf162 (layer-1 h)
    const float* __restrict__ Wr,
    float* __restrict__ partials) {
  __shared__ float blk[4];
  int wv = __builtin_amdgcn_readfirstlane((int)(threadIdx.x >> 6));
  int n = blockIdx.x * 4 + wv;
  int lane = threadIdx.x & 63;
  int c = min(cnt[n], SLOTS);
  int base = n * SLOTS;
  float2 acc0 = {0.f, 0.f}, acc1 = {0.f, 0.f}, acc2 = {0.f, 0.f}, acc3 = {0.f, 0.f};

#define EDGE_BODY(IDX)                                                         \
  {                                                                            \
    int s = src_perm[base + (IDX)];                                            \
    float4 a4 = a_perm[base + (IDX)];                                          \
    const __hip_bfloat162* zr = zb + (size_t)s * 256;                          \
    float2 v0 = __bfloat1622float2(zr[lane]);                                  \
    float2 v1 = __bfloat1622float2(zr[64 + lane]);                             \
    float2 v2 = __bfloat1622float2(zr[128 + lane]);                            \
    float2 v3 = __bfloat1622float2(zr[192 + lane]);                            \
    acc0.x += a4.x * v0.x; acc0.y += a4.x * v0.y;                              \
    acc1.x += a4.y * v1.x; acc1.y += a4.y * v1.y;                              \
    acc2.x += a4.z * v2.x; acc2.y += a4.z * v2.y;                              \
    acc3.x += a4.w * v3.x; acc3.y += a4.w * v3.y;                              \
  }

  int i = 0;
  for (; i + 1 < c; i += 2) {
    EDGE_BODY(i)
    EDGE_BODY(i + 1)
  }
  if (i < c) EDGE_BODY(i)
#undef EDGE_BODY

  float2 b0 = *reinterpret_cast<const float2*>(&bias[0 * ND + 2 * lane]);
  float2 b1 = *reinterpret_cast<const float2*>(&bias[1 * ND + 2 * lane]);
  float2 b2 = *reinterpret_cast<const float2*>(&bias[2 * ND + 2 * lane]);
  float2 b3 = *reinterpret_cast<const float2*>(&bias[3 * ND + 2 * lane]);
  float2 v0 = {acc0.x + b0.x, acc0.y + b0.y};
  float2 v1 = {acc1.x + b1.x, acc1.y + b1.y};
  float2 v2 = {acc2.x + b2.x, acc2.y + b2.y};
  float2 v3 = {acc3.x + b3.x, acc3.y + b3.y};
  if (ELU) {
    v0.x = (v0.x > 0.f) ? v0.x : expm1f(v0.x);
    v0.y = (v0.y > 0.f) ? v0.y : expm1f(v0.y);
    v1.x = (v1.x > 0.f) ? v1.x : expm1f(v1.x);
    v1.y = (v1.y > 0.f) ? v1.y : expm1f(v1.y);
    v2.x = (v2.x > 0.f) ? v2.x : expm1f(v2.x);
    v2.y = (v2.y > 0.f) ? v2.y : expm1f(v2.y);
    v3.x = (v3.x > 0.f) ? v3.x : expm1f(v3.x);
    v3.y = (v3.y > 0.f) ? v3.y : expm1f(v3.y);
  }
  if (!FINAL) {
    __hip_bfloat162* o = out + (size_t)n * 256;
    o[lane] = __float22bfloat162_rn(make_float2(v0.x, v0.y));
    o[64 + lane] = __float22bfloat162_rn(make_float2(v1.x, v1.y));
    o[128 + lane] = __float22bfloat162_rn(make_float2(v2.x, v2.y));
    o[192 + lane] = __float22bfloat162_rn(make_float2(v3.x, v3.y));
  } else {
    float2 wr = *reinterpret_cast<const float2*>(&Wr[2 * lane]);
    float p = 0.25f * ((v0.x + v1.x + v2.x + v3.x) * wr.x +
                       (v0.y + v1.y + v2.y + v3.y) * wr.y);
    for (int off = 32; off > 0; off >>= 1) p += __shfl_down(p, off);
    if (lane == 0) blk[threadIdx.x >> 6] = p;
    __syncthreads();
    if (threadIdx.x == 0) {
      float s = blk[0] + blk[1] + blk[2] + blk[3];
      atomicAdd(&partials[blockIdx.x & 255], s);
    }
  }
}

__global__ __launch_bounds__(256) void final_kernel(const float* __restrict__ partials,
                                                    const float* __restrict__ br,
                                                    float* __restrict__ out) {
  __shared__ float tmp[256];
  int t = threadIdx.x;
  tmp[t] = partials[t];
  __syncthreads();
  for (int off = 128; off > 0; off >>= 1) {
    if (t < off) tmp[t] += tmp[t + off];
    __syncthreads();
  }
  if (t == 0) out[0] = tmp[0] + (float)NN * br[0];
}

// ---------------- launch ----------------
extern "C" void kernel_launch(void* const* d_in, const int* in_sizes, int n_in,
                              void* d_out, int out_size, void* d_ws, size_t ws_size,
                              hipStream_t stream) {
  const float* feats = (const float*)d_in[0];
  const int* src = (const int*)d_in[1];
  const int* dst = (const int*)d_in[2];
  const float* W1 = (const float*)d_in[3];
  const float* al1 = (const float*)d_in[4];
  const float* ar1 = (const float*)d_in[5];
  const float* b1 = (const float*)d_in[6];
  const float* W2 = (const float*)d_in[7];
  const float* al2 = (const float*)d_in[8];
  const float* ar2 = (const float*)d_in[9];
  const float* b2 = (const float*)d_in[10];
  const float* Wr = (const float*)d_in[11];
  const float* br = (const float*)d_in[12];
  float* out = (float*)d_out;

  // workspace layout (~73 MB); all section sizes multiples of 16 B
  __hip_bfloat16* featsb = (__hip_bfloat16*)d_ws;       // MPAD*128 bf16
  __hip_bfloat16* zb = featsb + (size_t)MPAD * 128;     // MPAD*HD bf16 (z1, then z2)
  __hip_bfloat16* hb = zb + (size_t)MPAD * HD;          // MPAD*HD bf16 (h1)
  __hip_bfloat16* W1t = hb + (size_t)MPAD * HD;         // 512*128 bf16
  __hip_bfloat16* W2t = W1t + 512 * 128;                // 512*512 bf16
  float4* a_perm = (float4*)(W2t + 512 * 512);          // NN*SLOTS float4 (alpha)
  float* el = (float*)(a_perm + (size_t)NN * SLOTS);    // NN*4
  float* er = el + (size_t)NN * NHEAD;                  // NN*4
  float* partials = er + (size_t)NN * NHEAD;            // 256
  int* cnt = (int*)(partials + 256);                    // NN
  int* src_perm = cnt + NN;                             // NN*SLOTS

  const __hip_bfloat162* zb2 = (const __hip_bfloat162*)zb;

  // padded CSR by dst (rebuilt every call; ws is poisoned between calls)
  hipMemsetAsync(cnt, 0, NN * sizeof(int), stream);
  fill_kernel<<<(NE + 255) / 256, 256, 0, stream>>>(dst, src, cnt, src_perm);
  // zero hb pad rows (agg1 only writes NN rows; GEMM2 reads MPAD rows)
  hipMemsetAsync(hb + (size_t)NN * HD, 0, (size_t)(MPAD - NN) * HD * sizeof(__hip_bfloat16), stream);
  hipMemsetAsync(partials, 0, 256 * sizeof(float), stream);

  // dtype prep
  tobf16_pad_kernel<<<(MPAD * 128 + 255) / 256, 256, 0, stream>>>(
      feats, featsb, NN * 128, MPAD * 128);
  transpose_bf16_kernel<<<(128 * 512 + 255) / 256, 256, 0, stream>>>(W1, W1t, 128, 512);
  transpose_bf16_kernel<<<(512 * 512 + 255) / 256, 256, 0, stream>>>(W2, W2t, 512, 512);

  dim3 gemm_grid(MPAD / 128, NHEAD);

  // ---- layer 1 ----
  mfma_gemm_kernel<<<gemm_grid, 256, 0, stream>>>(featsb, W1t, zb, 128, al1, ar1, el, er);
  attn_kernel<<<NN / 4, 256, 0, stream>>>(src_perm, cnt, el, er, a_perm);
  aggregate_kernel<true, false><<<NN / 4, 256, 0, stream>>>(
      zb2, a_perm, cnt, src_perm, b1, (__hip_bfloat162*)hb, nullptr, nullptr);

  // ---- layer 2 ----
  mfma_gemm_kernel<<<gemm_grid, 256, 0, stream>>>(hb, W2t, zb, 512, al2, ar2, el, er);
  attn_kernel<<<NN / 4, 256, 0, stream>>>(src_perm, cnt, el, er, a_perm);
  aggregate_kernel<false, true><<<NN / 4, 256, 0, stream>>>(
      zb2, a_perm, cnt, src_perm, b2, nullptr, Wr, partials);
  final_kernel<<<1, 256, 0, stream>>>(partials, br, out);
}

// Round 5
// 251.716 us; speedup vs baseline: 3.0156x; 1.0374x over previous
//
#include <hip/hip_runtime.h>
#include <hip/hip_bf16.h>
#include <cstddef>

// Problem constants (match reference)
constexpr int NN = 20000;   // nodes
constexpr int NE = 320000;  // edges
constexpr int NHEAD = 4;
constexpr int ND = 128;     // per-head dim
constexpr int HD = 512;     // H*D
constexpr int MPAD = 20096; // 157 * 128, padded row count for GEMM tiles
constexpr int SLOTS = 64;   // padded-CSR slots per node (Poisson(16): P(>64)~1e-20)
constexpr float NEG_SLOPE = 0.2f;

using short8 = __attribute__((ext_vector_type(8))) short;
using f32x4 = __attribute__((ext_vector_type(4))) float;
using f32x2 = __attribute__((ext_vector_type(2))) float;

// async global->LDS, 16B per lane, LDS dest = wave-uniform base + lane*16
__device__ inline void gload16(const void* g, void* l) {
  __builtin_amdgcn_global_load_lds(
      (const __attribute__((address_space(1))) void*)g,
      (__attribute__((address_space(3))) void*)l, 16, 0, 0);
}

// fp8 e4m3 (OCP on gfx950) encode one float -> byte
__device__ inline unsigned char f32_to_fp8(float v) {
  int pk = __builtin_amdgcn_cvt_pk_fp8_f32(v, v, 0, false);
  return (unsigned char)(pk & 0xff);
}

// ---------------- padded-CSR fill: src_perm[d*64+p] = src, cnt via atomics ---
__global__ __launch_bounds__(256) void fill_kernel(const int* __restrict__ dst,
                                                   const int* __restrict__ src,
                                                   int* __restrict__ cnt,
                                                   int* __restrict__ src_perm) {
  int t = blockIdx.x * 256 + threadIdx.x;
  if (t < NE) {
    int d = dst[t];
    int p = atomicAdd(&cnt[d], 1);
    if (p < SLOTS) src_perm[d * SLOTS + p] = src[t];
  }
}

// ---------------- dtype prep ----------------
// fp32 -> bf16, zero-padding past n_valid
__global__ __launch_bounds__(256) void tobf16_pad_kernel(const float* __restrict__ X,
                                                         __hip_bfloat16* __restrict__ Y,
                                                         int n_valid, int n_total) {
  int t = blockIdx.x * 256 + threadIdx.x;
  if (t >= n_total) return;
  Y[t] = __float2bfloat16(t < n_valid ? X[t] : 0.f);
}

// W [K][M] fp32 -> Wt [M][K] bf16
__global__ __launch_bounds__(256) void transpose_bf16_kernel(const float* __restrict__ W,
                                                             __hip_bfloat16* __restrict__ Wt,
                                                             int K, int M) {
  int t = blockIdx.x * 256 + threadIdx.x;
  if (t >= K * M) return;
  int m = t / K, k = t - m * K;
  Wt[t] = __float2bfloat16(W[(size_t)k * M + m]);
}

// ---------------- bf16 MFMA GEMM + fused el/er epilogue, fp8 z output -------
// z[Mpad][512] (fp8 e4m3) = A[Mpad][K] @ Bt[512][K]^T.  128x128 tile, 256
// threads = 4 waves, each 64x64 via 4x4 mfma_16x16x32.  blockIdx.y = head
// (D=128 = tile width); block also reduces el/er = z . al/ar from the fp32
// accumulators (full precision) and stores them directly.  z is fp8 because
// its only consumer is the alpha-weighted aggregate payload.
__global__ __launch_bounds__(256) void mfma_gemm_kernel(
    const __hip_bfloat16* __restrict__ A,   // [Mpad][K] bf16 row-major
    const __hip_bfloat16* __restrict__ Bt,  // [512][K] bf16 row-major (B^T)
    unsigned char* __restrict__ C,          // [Mpad][512] fp8
    int K,
    const float* __restrict__ al,           // [4][128]
    const float* __restrict__ ar,           // [4][128]
    float* __restrict__ el,                 // [NN][4]
    float* __restrict__ er) {               // [NN][4]
  __shared__ short As[128 * 32];
  __shared__ short Bs[128 * 32];
  __shared__ float elbuf[4][128];
  __shared__ float erbuf[4][128];
  int t = threadIdx.x;
  int lane = t & 63;
  int wave = t >> 6;
  int rowBase = blockIdx.x * 128;
  int head = blockIdx.y;
  int colBase = head * 128;
  int woffr = (wave & 1) * 64;
  int woffc = (wave >> 1) * 64;
  int mrow = lane & 15, quad = lane >> 4;

  f32x4 acc[4][4];
#pragma unroll
  for (int i = 0; i < 4; ++i)
#pragma unroll
    for (int j = 0; j < 4; ++j) acc[i][j] = (f32x4){0.f, 0.f, 0.f, 0.f};

  for (int k0 = 0; k0 < K; k0 += 32) {
    // stage A tile [128][32] and Bt tile [128][32]; chunk f = (row f/4, k-chunk f%4)
#pragma unroll
    for (int p = 0; p < 2; ++p) {
      int f = p * 256 + wave * 64 + lane;
      int r = f >> 2, kc = f & 3;
      gload16(A + (size_t)(rowBase + r) * K + k0 + kc * 8,
              As + p * 2048 + wave * 512);
      gload16(Bt + (size_t)(colBase + r) * K + k0 + kc * 8,
              Bs + p * 2048 + wave * 512);
    }
    __syncthreads();
    short8 af[4], bfr[4];
#pragma unroll
    for (int i = 0; i < 4; ++i)
      af[i] = *(const short8*)&As[(woffr + i * 16 + mrow) * 32 + quad * 8];
#pragma unroll
    for (int j = 0; j < 4; ++j)
      bfr[j] = *(const short8*)&Bs[(woffc + j * 16 + mrow) * 32 + quad * 8];
#pragma unroll
    for (int i = 0; i < 4; ++i)
#pragma unroll
      for (int j = 0; j < 4; ++j)
        acc[i][j] = __builtin_amdgcn_mfma_f32_16x16x32_bf16(af[i], bfr[j], acc[i][j], 0, 0, 0);
    __syncthreads();
  }

  // C store (fp8). C/D layout: col = lane&15, row = quad*4 + reg (m89/m91)
#pragma unroll
  for (int i = 0; i < 4; ++i) {
#pragma unroll
    for (int j = 0; j < 4; ++j) {
      int col = colBase + woffc + j * 16 + mrow;
#pragma unroll
      for (int r = 0; r < 4; ++r) {
        int row = rowBase + woffr + i * 16 + quad * 4 + r;
        C[(size_t)row * HD + col] = f32_to_fp8(acc[i][j][r]);
      }
    }
  }

  // ---- fused el/er epilogue: el[row] = sum_col z[row,col]*al[head,col] ----
  float al_v[4], ar_v[4];
#pragma unroll
  for (int j = 0; j < 4; ++j) {
    int coll = woffc + j * 16 + mrow;
    al_v[j] = al[head * 128 + coll];
    ar_v[j] = ar[head * 128 + coll];
  }
#pragma unroll
  for (int i = 0; i < 4; ++i) {
#pragma unroll
    for (int r = 0; r < 4; ++r) {
      float pl = 0.f, pr = 0.f;
#pragma unroll
      for (int j = 0; j < 4; ++j) {
        float v = acc[i][j][r];
        pl += v * al_v[j];
        pr += v * ar_v[j];
      }
      // reduce over the 16 lanes (mrow) that share this row (xor stays in quad group)
#pragma unroll
      for (int off = 1; off < 16; off <<= 1) {
        pl += __shfl_xor(pl, off);
        pr += __shfl_xor(pr, off);
      }
      if (mrow == 0) {
        int row128 = woffr + i * 16 + quad * 4 + r;
        elbuf[wave][row128] = pl;
        erbuf[wave][row128] = pr;
      }
    }
  }
  __syncthreads();
  // waves (0: rows0-63/cols0-63, 1: rows64-127/cols0-63, 2: rows0-63/cols64-127,
  //        3: rows64-127/cols64-127) -> combine col halves
  if (t < 128) {
    int row = t;
    float ev, rv;
    if (row < 64) { ev = elbuf[0][row] + elbuf[2][row]; rv = erbuf[0][row] + erbuf[2][row]; }
    else          { ev = elbuf[1][row] + elbuf[3][row]; rv = erbuf[1][row] + erbuf[3][row]; }
    int gr = rowBase + row;
    if (gr < NN) {
      el[gr * 4 + head] = ev;
      er[gr * 4 + head] = rv;
    }
  }
}

// ---------------- per-node attention: one wave per node, lane = slot ---------
// a = exp(leaky_relu(el[src]+er[n])) (softmax shift-invariance -> segment_max
// skipped; |e| small). Wave-reduce denom, store pre-normalized alpha (fp32).
__global__ __launch_bounds__(256) void attn_kernel(const int* __restrict__ src_perm,
                                                   const int* __restrict__ cnt,
                                                   const float* __restrict__ el,
                                                   const float* __restrict__ er,
                                                   float4* __restrict__ a_perm) {
  int wv = __builtin_amdgcn_readfirstlane((int)(threadIdx.x >> 6));
  int n = blockIdx.x * 4 + wv;
  int lane = threadIdx.x & 63;
  int c = min(cnt[n], SLOTS);
  float4 er4 = *reinterpret_cast<const float4*>(&er[n * 4]);
  float a0 = 0.f, a1 = 0.f, a2 = 0.f, a3 = 0.f;
  bool act = lane < c;
  if (act) {
    int s = src_perm[n * SLOTS + lane];
    float4 e4 = *reinterpret_cast<const float4*>(&el[s * 4]);
    float x0 = e4.x + er4.x, x1 = e4.y + er4.y;
    float x2 = e4.z + er4.z, x3 = e4.w + er4.w;
    x0 = (x0 > 0.f) ? x0 : NEG_SLOPE * x0;
    x1 = (x1 > 0.f) ? x1 : NEG_SLOPE * x1;
    x2 = (x2 > 0.f) ? x2 : NEG_SLOPE * x2;
    x3 = (x3 > 0.f) ? x3 : NEG_SLOPE * x3;
    a0 = __expf(x0); a1 = __expf(x1); a2 = __expf(x2); a3 = __expf(x3);
  }
  float s0 = a0, s1 = a1, s2 = a2, s3 = a3;
#pragma unroll
  for (int off = 1; off < 64; off <<= 1) {
    s0 += __shfl_xor(s0, off);
    s1 += __shfl_xor(s1, off);
    s2 += __shfl_xor(s2, off);
    s3 += __shfl_xor(s3, off);
  }
  if (act) {
    float4 r;
    r.x = a0 / fmaxf(s0, 1e-9f);
    r.y = a1 / fmaxf(s1, 1e-9f);
    r.z = a2 / fmaxf(s2, 1e-9f);
    r.w = a3 / fmaxf(s3, 1e-9f);
    a_perm[n * SLOTS + lane] = r;
  }
}

// ---------------- aggregation: one wave per node, fp8 payload ---------------
// out[n,h,:] = sum_e alpha[e,h] * z[src,h,:] + bias.  Lane l owns the 8
// consecutive dims [l*8, l*8+8) of the flattened 512-dim row (head = l>>4):
// ONE global_load_dwordx2 per edge per lane, decoded with v_cvt_pk_f32_fp8.
// alpha/src loads are wave-uniform (scalar); only z rows are random gathers.
template <bool ELU, bool FINAL>
__global__ __launch_bounds__(256) void aggregate_kernel(
    const unsigned char* __restrict__ zf8,  // [MPAD][512] fp8
    const float4* __restrict__ a_perm,
    const int* __restrict__ cnt,
    const int* __restrict__ src_perm,
    const float* __restrict__ bias,
    __hip_bfloat16* __restrict__ out,       // [NN][512] bf16 (layer-1 h)
    const float* __restrict__ Wr,
    float* __restrict__ partials) {
  __shared__ float blk[4];
  int wv = __builtin_amdgcn_readfirstlane((int)(threadIdx.x >> 6));
  int n = blockIdx.x * 4 + wv;
  int lane = threadIdx.x & 63;
  int head = lane >> 4;
  int c = min(cnt[n], SLOTS);
  int base = n * SLOTS;
  float acc[8] = {};

#define EDGE_BODY(IDX)                                                         \
  {                                                                            \
    int s = src_perm[base + (IDX)];                                            \
    float4 a4 = a_perm[base + (IDX)];                                          \
    float a = (head & 2) ? ((head & 1) ? a4.w : a4.z)                          \
                         : ((head & 1) ? a4.y : a4.x);                         \
    uint2 w = *reinterpret_cast<const uint2*>(zf8 + (size_t)s * 512 + lane * 8); \
    f32x2 f0 = __builtin_amdgcn_cvt_pk_f32_fp8(w.x, false);                    \
    f32x2 f1 = __builtin_amdgcn_cvt_pk_f32_fp8(w.x, true);                     \
    f32x2 f2 = __builtin_amdgcn_cvt_pk_f32_fp8(w.y, false);                    \
    f32x2 f3 = __builtin_amdgcn_cvt_pk_f32_fp8(w.y, true);                     \
    acc[0] += a * f0.x; acc[1] += a * f0.y;                                    \
    acc[2] += a * f1.x; acc[3] += a * f1.y;                                    \
    acc[4] += a * f2.x; acc[5] += a * f2.y;                                    \
    acc[6] += a * f3.x; acc[7] += a * f3.y;                                    \
  }

  int i = 0;
  for (; i + 1 < c; i += 2) {
    EDGE_BODY(i)
    EDGE_BODY(i + 1)
  }
  if (i < c) EDGE_BODY(i)
#undef EDGE_BODY

  // bias[l*8+j] == bias[head*128 + dim] for this lane's dims
  float4 bA = *reinterpret_cast<const float4*>(&bias[lane * 8]);
  float4 bB = *reinterpret_cast<const float4*>(&bias[lane * 8 + 4]);
  float v[8];
  v[0] = acc[0] + bA.x; v[1] = acc[1] + bA.y;
  v[2] = acc[2] + bA.z; v[3] = acc[3] + bA.w;
  v[4] = acc[4] + bB.x; v[5] = acc[5] + bB.y;
  v[6] = acc[6] + bB.z; v[7] = acc[7] + bB.w;
  if (ELU) {
#pragma unroll
    for (int j = 0; j < 8; ++j) v[j] = (v[j] > 0.f) ? v[j] : expm1f(v[j]);
  }
  if (!FINAL) {
    __hip_bfloat162 o[4];
#pragma unroll
    for (int j = 0; j < 4; ++j)
      o[j] = __float22bfloat162_rn(make_float2(v[2 * j], v[2 * j + 1]));
    *reinterpret_cast<uint4*>(out + (size_t)n * HD + lane * 8) =
        *reinterpret_cast<const uint4*>(o);
  } else {
    // pred_n = 0.25 * sum_h sum_d agg[h][d] * Wr[d]; lane's Wr slice repeats
    // every 128 dims: Wr[(lane&15)*8 + j]
    float4 wA = *reinterpret_cast<const float4*>(&Wr[(lane & 15) * 8]);
    float4 wB = *reinterpret_cast<const float4*>(&Wr[(lane & 15) * 8 + 4]);
    float p = v[0] * wA.x + v[1] * wA.y + v[2] * wA.z + v[3] * wA.w +
              v[4] * wB.x + v[5] * wB.y + v[6] * wB.z + v[7] * wB.w;
    p *= 0.25f;
    for (int off = 32; off > 0; off >>= 1) p += __shfl_down(p, off);
    if (lane == 0) blk[threadIdx.x >> 6] = p;
    __syncthreads();
    if (threadIdx.x == 0) {
      float s = blk[0] + blk[1] + blk[2] + blk[3];
      atomicAdd(&partials[blockIdx.x & 255], s);
    }
  }
}

__global__ __launch_bounds__(256) void final_kernel(const float* __restrict__ partials,
                                                    const float* __restrict__ br,
                                                    float* __restrict__ out) {
  __shared__ float tmp[256];
  int t = threadIdx.x;
  tmp[t] = partials[t];
  __syncthreads();
  for (int off = 128; off > 0; off >>= 1) {
    if (t < off) tmp[t] += tmp[t + off];
    __syncthreads();
  }
  if (t == 0) out[0] = tmp[0] + (float)NN * br[0];
}

// ---------------- launch ----------------
extern "C" void kernel_launch(void* const* d_in, const int* in_sizes, int n_in,
                              void* d_out, int out_size, void* d_ws, size_t ws_size,
                              hipStream_t stream) {
  const float* feats = (const float*)d_in[0];
  const int* src = (const int*)d_in[1];
  const int* dst = (const int*)d_in[2];
  const float* W1 = (const float*)d_in[3];
  const float* al1 = (const float*)d_in[4];
  const float* ar1 = (const float*)d_in[5];
  const float* b1 = (const float*)d_in[6];
  const float* W2 = (const float*)d_in[7];
  const float* al2 = (const float*)d_in[8];
  const float* ar2 = (const float*)d_in[9];
  const float* b2 = (const float*)d_in[10];
  const float* Wr = (const float*)d_in[11];
  const float* br = (const float*)d_in[12];
  float* out = (float*)d_out;

  // workspace layout (~63 MB); all section sizes multiples of 16 B
  __hip_bfloat16* featsb = (__hip_bfloat16*)d_ws;       // MPAD*128 bf16
  unsigned char* zf8 = (unsigned char*)(featsb + (size_t)MPAD * 128); // MPAD*HD fp8
  __hip_bfloat16* hb = (__hip_bfloat16*)(zf8 + (size_t)MPAD * HD);    // MPAD*HD bf16 (h1)
  __hip_bfloat16* W1t = hb + (size_t)MPAD * HD;         // 512*128 bf16
  __hip_bfloat16* W2t = W1t + 512 * 128;                // 512*512 bf16
  float4* a_perm = (float4*)(W2t + 512 * 512);          // NN*SLOTS float4 (alpha)
  float* el = (float*)(a_perm + (size_t)NN * SLOTS);    // NN*4
  float* er = el + (size_t)NN * NHEAD;                  // NN*4
  float* partials = er + (size_t)NN * NHEAD;            // 256
  int* cnt = (int*)(partials + 256);                    // NN
  int* src_perm = cnt + NN;                             // NN*SLOTS

  // padded CSR by dst (rebuilt every call; ws is poisoned between calls)
  hipMemsetAsync(cnt, 0, NN * sizeof(int), stream);
  fill_kernel<<<(NE + 255) / 256, 256, 0, stream>>>(dst, src, cnt, src_perm);
  // zero hb pad rows (agg1 only writes NN rows; GEMM2 reads MPAD rows)
  hipMemsetAsync(hb + (size_t)NN * HD, 0, (size_t)(MPAD - NN) * HD * sizeof(__hip_bfloat16), stream);
  hipMemsetAsync(partials, 0, 256 * sizeof(float), stream);

  // dtype prep
  tobf16_pad_kernel<<<(MPAD * 128 + 255) / 256, 256, 0, stream>>>(
      feats, featsb, NN * 128, MPAD * 128);
  transpose_bf16_kernel<<<(128 * 512 + 255) / 256, 256, 0, stream>>>(W1, W1t, 128, 512);
  transpose_bf16_kernel<<<(512 * 512 + 255) / 256, 256, 0, stream>>>(W2, W2t, 512, 512);

  dim3 gemm_grid(MPAD / 128, NHEAD);

  // ---- layer 1 ----
  mfma_gemm_kernel<<<gemm_grid, 256, 0, stream>>>(featsb, W1t, zf8, 128, al1, ar1, el, er);
  attn_kernel<<<NN / 4, 256, 0, stream>>>(src_perm, cnt, el, er, a_perm);
  aggregate_kernel<true, false><<<NN / 4, 256, 0, stream>>>(
      zf8, a_perm, cnt, src_perm, b1, hb, nullptr, nullptr);

  // ---- layer 2 ----
  mfma_gemm_kernel<<<gemm_grid, 256, 0, stream>>>(hb, W2t, zf8, 512, al2, ar2, el, er);
  attn_kernel<<<NN / 4, 256, 0, stream>>>(src_perm, cnt, el, er, a_perm);
  aggregate_kernel<false, true><<<NN / 4, 256, 0, stream>>>(
      zf8, a_perm, cnt, src_perm, b2, nullptr, Wr, partials);
  final_kernel<<<1, 256, 0, stream>>>(partials, br, out);
}

// Round 6
// 206.250 us; speedup vs baseline: 3.6803x; 1.2204x over previous
//
#include <hip/hip_runtime.h>
#include <hip/hip_bf16.h>
#include <cstddef>

// Problem constants (match reference)
constexpr int NN = 20000;   // nodes
constexpr int NE = 320000;  // edges
constexpr int NHEAD = 4;
constexpr int ND = 128;     // per-head dim
constexpr int HD = 512;     // H*D
constexpr int MPAD = 20096; // 157 * 128, padded row count for GEMM tiles
constexpr int SLOTS = 64;   // padded-CSR slots per node (Poisson(16): P(>64)~1e-20)
constexpr float NEG_SLOPE = 0.2f;

using short8 = __attribute__((ext_vector_type(8))) short;
using f32x4 = __attribute__((ext_vector_type(4))) float;
using f32x2 = __attribute__((ext_vector_type(2))) float;

// async global->LDS, 16B per lane, LDS dest = wave-uniform base + lane*16
__device__ inline void gload16(const void* g, void* l) {
  __builtin_amdgcn_global_load_lds(
      (const __attribute__((address_space(1))) void*)g,
      (__attribute__((address_space(3))) void*)l, 16, 0, 0);
}

// fp8 e4m3 (OCP on gfx950) encode one float -> byte
__device__ inline unsigned char f32_to_fp8(float v) {
  int pk = __builtin_amdgcn_cvt_pk_fp8_f32(v, v, 0, false);
  return (unsigned char)(pk & 0xff);
}

// ---------------- padded-CSR fill: src_perm[d*64+p] = src, cnt via atomics ---
__global__ __launch_bounds__(256) void fill_kernel(const int* __restrict__ dst,
                                                   const int* __restrict__ src,
                                                   int* __restrict__ cnt,
                                                   int* __restrict__ src_perm) {
  int t = blockIdx.x * 256 + threadIdx.x;
  if (t < NE) {
    int d = dst[t];
    int p = atomicAdd(&cnt[d], 1);
    if (p < SLOTS) src_perm[d * SLOTS + p] = src[t];
  }
}

// ---------------- fused prep: feats->bf16 pad, W1^T, W2^T, zero hb pad,
// zero partials.  One grid-stride-free kernel over concatenated segments. ----
constexpr int P0 = MPAD * 128;              // featsb
constexpr int P1 = P0 + 512 * 128;          // W1t
constexpr int P2 = P1 + 512 * 512;          // W2t
constexpr int P3 = P2 + (MPAD - NN) * HD;   // hb pad zero
constexpr int P4 = P3 + 256;                // partials zero
__global__ __launch_bounds__(256) void prep_kernel(
    const float* __restrict__ feats, const float* __restrict__ W1,
    const float* __restrict__ W2,
    __hip_bfloat16* __restrict__ featsb, __hip_bfloat16* __restrict__ W1t,
    __hip_bfloat16* __restrict__ W2t, __hip_bfloat16* __restrict__ hb,
    float* __restrict__ partials) {
  int t = blockIdx.x * 256 + threadIdx.x;
  if (t < P0) {
    featsb[t] = __float2bfloat16(t < NN * 128 ? feats[t] : 0.f);
  } else if (t < P1) {
    int u = t - P0;                       // W1t[m][k], m=u>>7, k=u&127
    W1t[u] = __float2bfloat16(W1[(size_t)(u & 127) * 512 + (u >> 7)]);
  } else if (t < P2) {
    int u = t - P1;                       // W2t[m][k], m=u>>9, k=u&511
    W2t[u] = __float2bfloat16(W2[(size_t)(u & 511) * 512 + (u >> 9)]);
  } else if (t < P3) {
    int u = t - P2;
    hb[(size_t)NN * HD + u] = __float2bfloat16(0.f);
  } else if (t < P4) {
    partials[t - P3] = 0.f;
  }
}

// ---------------- bf16 MFMA GEMM + fused el/er epilogue, fp8 z output -------
// z[Mpad][512] (fp8 e4m3) = A[Mpad][K] @ Bt[512][K]^T.  128x128 tile, 256
// threads = 4 waves, each 64x64 via 4x4 mfma_16x16x32.  blockIdx.y = head
// (D=128 = tile width); block also reduces el/er = z . al/ar from the fp32
// accumulators (full precision) and stores them directly.  z is fp8 because
// its only consumer is the alpha-weighted aggregate payload.
__global__ __launch_bounds__(256) void mfma_gemm_kernel(
    const __hip_bfloat16* __restrict__ A,   // [Mpad][K] bf16 row-major
    const __hip_bfloat16* __restrict__ Bt,  // [512][K] bf16 row-major (B^T)
    unsigned char* __restrict__ C,          // [Mpad][512] fp8
    int K,
    const float* __restrict__ al,           // [4][128]
    const float* __restrict__ ar,           // [4][128]
    float* __restrict__ el,                 // [NN][4]
    float* __restrict__ er) {               // [NN][4]
  __shared__ short As[128 * 32];
  __shared__ short Bs[128 * 32];
  __shared__ float elbuf[4][128];
  __shared__ float erbuf[4][128];
  int t = threadIdx.x;
  int lane = t & 63;
  int wave = t >> 6;
  int rowBase = blockIdx.x * 128;
  int head = blockIdx.y;
  int colBase = head * 128;
  int woffr = (wave & 1) * 64;
  int woffc = (wave >> 1) * 64;
  int mrow = lane & 15, quad = lane >> 4;

  f32x4 acc[4][4];
#pragma unroll
  for (int i = 0; i < 4; ++i)
#pragma unroll
    for (int j = 0; j < 4; ++j) acc[i][j] = (f32x4){0.f, 0.f, 0.f, 0.f};

  for (int k0 = 0; k0 < K; k0 += 32) {
    // stage A tile [128][32] and Bt tile [128][32]; chunk f = (row f/4, k-chunk f%4)
#pragma unroll
    for (int p = 0; p < 2; ++p) {
      int f = p * 256 + wave * 64 + lane;
      int r = f >> 2, kc = f & 3;
      gload16(A + (size_t)(rowBase + r) * K + k0 + kc * 8,
              As + p * 2048 + wave * 512);
      gload16(Bt + (size_t)(colBase + r) * K + k0 + kc * 8,
              Bs + p * 2048 + wave * 512);
    }
    __syncthreads();
    short8 af[4], bfr[4];
#pragma unroll
    for (int i = 0; i < 4; ++i)
      af[i] = *(const short8*)&As[(woffr + i * 16 + mrow) * 32 + quad * 8];
#pragma unroll
    for (int j = 0; j < 4; ++j)
      bfr[j] = *(const short8*)&Bs[(woffc + j * 16 + mrow) * 32 + quad * 8];
#pragma unroll
    for (int i = 0; i < 4; ++i)
#pragma unroll
      for (int j = 0; j < 4; ++j)
        acc[i][j] = __builtin_amdgcn_mfma_f32_16x16x32_bf16(af[i], bfr[j], acc[i][j], 0, 0, 0);
    __syncthreads();
  }

  // C store (fp8). C/D layout: col = lane&15, row = quad*4 + reg (m89/m91)
#pragma unroll
  for (int i = 0; i < 4; ++i) {
#pragma unroll
    for (int j = 0; j < 4; ++j) {
      int col = colBase + woffc + j * 16 + mrow;
#pragma unroll
      for (int r = 0; r < 4; ++r) {
        int row = rowBase + woffr + i * 16 + quad * 4 + r;
        C[(size_t)row * HD + col] = f32_to_fp8(acc[i][j][r]);
      }
    }
  }

  // ---- fused el/er epilogue: el[row] = sum_col z[row,col]*al[head,col] ----
  float al_v[4], ar_v[4];
#pragma unroll
  for (int j = 0; j < 4; ++j) {
    int coll = woffc + j * 16 + mrow;
    al_v[j] = al[head * 128 + coll];
    ar_v[j] = ar[head * 128 + coll];
  }
#pragma unroll
  for (int i = 0; i < 4; ++i) {
#pragma unroll
    for (int r = 0; r < 4; ++r) {
      float pl = 0.f, pr = 0.f;
#pragma unroll
      for (int j = 0; j < 4; ++j) {
        float v = acc[i][j][r];
        pl += v * al_v[j];
        pr += v * ar_v[j];
      }
      // reduce over the 16 lanes (mrow) that share this row (xor stays in quad group)
#pragma unroll
      for (int off = 1; off < 16; off <<= 1) {
        pl += __shfl_xor(pl, off);
        pr += __shfl_xor(pr, off);
      }
      if (mrow == 0) {
        int row128 = woffr + i * 16 + quad * 4 + r;
        elbuf[wave][row128] = pl;
        erbuf[wave][row128] = pr;
      }
    }
  }
  __syncthreads();
  // waves (0: rows0-63/cols0-63, 1: rows64-127/cols0-63, 2: rows0-63/cols64-127,
  //        3: rows64-127/cols64-127) -> combine col halves
  if (t < 128) {
    int row = t;
    float ev, rv;
    if (row < 64) { ev = elbuf[0][row] + elbuf[2][row]; rv = erbuf[0][row] + erbuf[2][row]; }
    else          { ev = elbuf[1][row] + elbuf[3][row]; rv = erbuf[1][row] + erbuf[3][row]; }
    int gr = rowBase + row;
    if (gr < NN) {
      el[gr * 4 + head] = ev;
      er[gr * 4 + head] = rv;
    }
  }
}

// ---------------- fused attention + aggregation: one wave per node ----------
// Phase 1 (lane = slot): a = exp(leaky_relu(el[src]+er[n])) (softmax shift-
// invariance -> segment_max skipped; |e| small), wave-reduce denom, park
// normalized alpha in LDS (same-wave, no barrier needed).
// Phase 2 (lane = dims): out[n,h,:] = sum_e alpha[e,h]*z[src,h,:] + bias.
// Lane l owns dims [l*8, l*8+8) of the 512-dim row (head = l>>4): ONE
// global_load_dwordx2 per edge per lane, decoded with v_cvt_pk_f32_fp8.
template <bool ELU, bool FINAL>
__global__ __launch_bounds__(256) void aggregate_kernel(
    const unsigned char* __restrict__ zf8,  // [MPAD][512] fp8
    const int* __restrict__ cnt,
    const int* __restrict__ src_perm,
    const float* __restrict__ el,
    const float* __restrict__ er,
    const float* __restrict__ bias,
    __hip_bfloat16* __restrict__ out,       // [NN][512] bf16 (layer-1 h)
    const float* __restrict__ Wr,
    float* __restrict__ partials) {
  __shared__ float4 alds[4][SLOTS];
  __shared__ float blk[4];
  int wv = __builtin_amdgcn_readfirstlane((int)(threadIdx.x >> 6));
  int n = blockIdx.x * 4 + wv;
  int lane = threadIdx.x & 63;
  int c = min(cnt[n], SLOTS);
  int base = n * SLOTS;

  // ---- phase 1: attention coefficients (lane = slot) ----
  {
    float4 er4 = *reinterpret_cast<const float4*>(&er[n * 4]);
    float a0 = 0.f, a1 = 0.f, a2 = 0.f, a3 = 0.f;
    if (lane < c) {
      int s = src_perm[base + lane];
      float4 e4 = *reinterpret_cast<const float4*>(&el[s * 4]);
      float x0 = e4.x + er4.x, x1 = e4.y + er4.y;
      float x2 = e4.z + er4.z, x3 = e4.w + er4.w;
      x0 = (x0 > 0.f) ? x0 : NEG_SLOPE * x0;
      x1 = (x1 > 0.f) ? x1 : NEG_SLOPE * x1;
      x2 = (x2 > 0.f) ? x2 : NEG_SLOPE * x2;
      x3 = (x3 > 0.f) ? x3 : NEG_SLOPE * x3;
      a0 = __expf(x0); a1 = __expf(x1); a2 = __expf(x2); a3 = __expf(x3);
    }
    float s0 = a0, s1 = a1, s2 = a2, s3 = a3;
#pragma unroll
    for (int off = 1; off < 64; off <<= 1) {
      s0 += __shfl_xor(s0, off);
      s1 += __shfl_xor(s1, off);
      s2 += __shfl_xor(s2, off);
      s3 += __shfl_xor(s3, off);
    }
    float4 av;
    av.x = a0 / fmaxf(s0, 1e-9f);
    av.y = a1 / fmaxf(s1, 1e-9f);
    av.z = a2 / fmaxf(s2, 1e-9f);
    av.w = a3 / fmaxf(s3, 1e-9f);
    alds[wv][lane] = av;   // same-wave producer/consumer; compiler emits lgkmcnt wait
  }

  // ---- phase 2: payload aggregation (lane = dims) ----
  int head = lane >> 4;
  float acc[8] = {};

#define EDGE_BODY(IDX)                                                         \
  {                                                                            \
    int s = src_perm[base + (IDX)];                                            \
    float4 a4 = alds[wv][(IDX)];                                               \
    float a = (head & 2) ? ((head & 1) ? a4.w : a4.z)                          \
                         : ((head & 1) ? a4.y : a4.x);                         \
    uint2 w = *reinterpret_cast<const uint2*>(zf8 + (size_t)s * 512 + lane * 8); \
    f32x2 f0 = __builtin_amdgcn_cvt_pk_f32_fp8(w.x, false);                    \
    f32x2 f1 = __builtin_amdgcn_cvt_pk_f32_fp8(w.x, true);                     \
    f32x2 f2 = __builtin_amdgcn_cvt_pk_f32_fp8(w.y, false);                    \
    f32x2 f3 = __builtin_amdgcn_cvt_pk_f32_fp8(w.y, true);                     \
    acc[0] += a * f0.x; acc[1] += a * f0.y;                                    \
    acc[2] += a * f1.x; acc[3] += a * f1.y;                                    \
    acc[4] += a * f2.x; acc[5] += a * f2.y;                                    \
    acc[6] += a * f3.x; acc[7] += a * f3.y;                                    \
  }

  int i = 0;
  for (; i + 3 < c; i += 4) {
    EDGE_BODY(i)
    EDGE_BODY(i + 1)
    EDGE_BODY(i + 2)
    EDGE_BODY(i + 3)
  }
  for (; i < c; ++i) EDGE_BODY(i)
#undef EDGE_BODY

  // bias[l*8+j] == bias[head*128 + dim] for this lane's dims
  float4 bA = *reinterpret_cast<const float4*>(&bias[lane * 8]);
  float4 bB = *reinterpret_cast<const float4*>(&bias[lane * 8 + 4]);
  float v[8];
  v[0] = acc[0] + bA.x; v[1] = acc[1] + bA.y;
  v[2] = acc[2] + bA.z; v[3] = acc[3] + bA.w;
  v[4] = acc[4] + bB.x; v[5] = acc[5] + bB.y;
  v[6] = acc[6] + bB.z; v[7] = acc[7] + bB.w;
  if (ELU) {
#pragma unroll
    for (int j = 0; j < 8; ++j) v[j] = (v[j] > 0.f) ? v[j] : expm1f(v[j]);
  }
  if (!FINAL) {
    __hip_bfloat162 o[4];
#pragma unroll
    for (int j = 0; j < 4; ++j)
      o[j] = __float22bfloat162_rn(make_float2(v[2 * j], v[2 * j + 1]));
    *reinterpret_cast<uint4*>(out + (size_t)n * HD + lane * 8) =
        *reinterpret_cast<const uint4*>(o);
  } else {
    // pred_n = 0.25 * sum_h sum_d agg[h][d] * Wr[d]; lane's Wr slice repeats
    // every 128 dims: Wr[(lane&15)*8 + j]
    float4 wA = *reinterpret_cast<const float4*>(&Wr[(lane & 15) * 8]);
    float4 wB = *reinterpret_cast<const float4*>(&Wr[(lane & 15) * 8 + 4]);
    float p = v[0] * wA.x + v[1] * wA.y + v[2] * wA.z + v[3] * wA.w +
              v[4] * wB.x + v[5] * wB.y + v[6] * wB.z + v[7] * wB.w;
    p *= 0.25f;
    for (int off = 32; off > 0; off >>= 1) p += __shfl_down(p, off);
    if (lane == 0) blk[threadIdx.x >> 6] = p;
    __syncthreads();
    if (threadIdx.x == 0) {
      float s = blk[0] + blk[1] + blk[2] + blk[3];
      atomicAdd(&partials[blockIdx.x & 255], s);
    }
  }
}

__global__ __launch_bounds__(256) void final_kernel(const float* __restrict__ partials,
                                                    const float* __restrict__ br,
                                                    float* __restrict__ out) {
  __shared__ float tmp[256];
  int t = threadIdx.x;
  tmp[t] = partials[t];
  __syncthreads();
  for (int off = 128; off > 0; off >>= 1) {
    if (t < off) tmp[t] += tmp[t + off];
    __syncthreads();
  }
  if (t == 0) out[0] = tmp[0] + (float)NN * br[0];
}

// ---------------- launch ----------------
extern "C" void kernel_launch(void* const* d_in, const int* in_sizes, int n_in,
                              void* d_out, int out_size, void* d_ws, size_t ws_size,
                              hipStream_t stream) {
  const float* feats = (const float*)d_in[0];
  const int* src = (const int*)d_in[1];
  const int* dst = (const int*)d_in[2];
  const float* W1 = (const float*)d_in[3];
  const float* al1 = (const float*)d_in[4];
  const float* ar1 = (const float*)d_in[5];
  const float* b1 = (const float*)d_in[6];
  const float* W2 = (const float*)d_in[7];
  const float* al2 = (const float*)d_in[8];
  const float* ar2 = (const float*)d_in[9];
  const float* b2 = (const float*)d_in[10];
  const float* Wr = (const float*)d_in[11];
  const float* br = (const float*)d_in[12];
  float* out = (float*)d_out;

  // workspace layout (~42 MB); all section sizes multiples of 16 B
  __hip_bfloat16* featsb = (__hip_bfloat16*)d_ws;       // MPAD*128 bf16
  unsigned char* zf8 = (unsigned char*)(featsb + (size_t)MPAD * 128); // MPAD*HD fp8
  __hip_bfloat16* hb = (__hip_bfloat16*)(zf8 + (size_t)MPAD * HD);    // MPAD*HD bf16 (h1)
  __hip_bfloat16* W1t = hb + (size_t)MPAD * HD;         // 512*128 bf16
  __hip_bfloat16* W2t = W1t + 512 * 128;                // 512*512 bf16
  float* el = (float*)(W2t + 512 * 512);                // NN*4
  float* er = el + (size_t)NN * NHEAD;                  // NN*4
  float* partials = er + (size_t)NN * NHEAD;            // 256
  int* cnt = (int*)(partials + 256);                    // NN
  int* src_perm = cnt + NN;                             // NN*SLOTS

  // padded CSR by dst (rebuilt every call; ws is poisoned between calls)
  hipMemsetAsync(cnt, 0, NN * sizeof(int), stream);
  fill_kernel<<<(NE + 255) / 256, 256, 0, stream>>>(dst, src, cnt, src_perm);

  // fused prep: feats->bf16 pad, W transposes, hb pad zero, partials zero
  prep_kernel<<<(P4 + 255) / 256, 256, 0, stream>>>(feats, W1, W2, featsb, W1t,
                                                    W2t, hb, partials);

  dim3 gemm_grid(MPAD / 128, NHEAD);

  // ---- layer 1 ----
  mfma_gemm_kernel<<<gemm_grid, 256, 0, stream>>>(featsb, W1t, zf8, 128, al1, ar1, el, er);
  aggregate_kernel<true, false><<<NN / 4, 256, 0, stream>>>(
      zf8, cnt, src_perm, el, er, b1, hb, nullptr, nullptr);

  // ---- layer 2 ----
  mfma_gemm_kernel<<<gemm_grid, 256, 0, stream>>>(hb, W2t, zf8, 512, al2, ar2, el, er);
  aggregate_kernel<false, true><<<NN / 4, 256, 0, stream>>>(
      zf8, cnt, src_perm, el, er, b2, nullptr, Wr, partials);
  final_kernel<<<1, 256, 0, stream>>>(partials, br, out);
}